// Round 3
// baseline (946.089 us; speedup 1.0000x reference)
//
#include <hip/hip_runtime.h>
#include <hip/hip_bf16.h>
#include <stdint.h>

// Sizes: BS=64, M=1000, CLIP=512, D=512, N_WAYS=20, N_Z=8
// out = [logits (8,64,1000,20) | z (8,64,20,512) | mu (64,20,512) | scale (64,20,512)]

__device__ __forceinline__ float gelu_f(float x) {
    return 0.5f * x * (1.0f + erff(x * 0.70710678118654752440f));
}
__device__ __forceinline__ float softplus_f(float x) {
    return fmaxf(x, 0.0f) + log1pf(expf(-fabsf(x)));
}

// ---------------- threefry2x32 (matches JAX _threefry2x32_lowering) ----------------
__device__ __forceinline__ void threefry2x32(uint32_t k0, uint32_t k1,
                                             uint32_t x0, uint32_t x1,
                                             uint32_t& o0, uint32_t& o1) {
    uint32_t ks[3] = {k0, k1, k0 ^ k1 ^ 0x1BD11BDAu};
    x0 += ks[0]; x1 += ks[1];
    const uint32_t rot[8] = {13,15,26,6,17,29,16,24};
#pragma unroll
    for (int i = 0; i < 5; i++) {
#pragma unroll
        for (int j = 0; j < 4; j++) {
            uint32_t r = rot[(i & 1) * 4 + j];
            x0 += x1;
            x1 = (x1 << r) | (x1 >> (32 - r));
            x1 ^= x0;
        }
        x0 += ks[(i + 1) % 3];
        x1 += ks[(i + 2) % 3] + (uint32_t)(i + 1);
    }
    o0 = x0; o1 = x1;
}

__device__ __forceinline__ float bits_to_normal(uint32_t b) {
    float f = __uint_as_float((b >> 9) | 0x3F800000u) - 1.0f;
    const float lo = __uint_as_float(0xBF7FFFFFu); // nextafter(-1,0)
    float u = fmaxf(lo, f * 2.0f + lo);            // (1-lo) rounds to 2.0f
    return 1.41421356237309504880f * erfinvf(u);
}

// ---------------- K1: class scatter partials (deterministic) ----------------
__global__ __launch_bounds__(512) void scatter_k(const float* __restrict__ xc,
                                                 const int* __restrict__ y,
                                                 float* __restrict__ Apart,
                                                 float* __restrict__ cntpart) {
    __shared__ float sA[20 * 512];
    __shared__ float scnt[20];
    const int b = blockIdx.x, ch = blockIdx.y;
    const int tid = threadIdx.x;
    for (int i = tid; i < 20 * 512; i += 512) sA[i] = 0.f;
    if (tid < 20) scnt[tid] = 0.f;
    __syncthreads();
    const int m0 = ch * 125, m1 = m0 + 125;
    for (int m = m0; m < m1; m++) {
        int cls = y[b * 1000 + m];
        sA[cls * 512 + tid] += xc[((size_t)b * 1000 + m) * 512 + tid];
        if (tid == 0) scnt[cls] += 1.f;
    }
    __syncthreads();
    float* dst = Apart + (size_t)ch * 655360 + (size_t)b * 10240;
    for (int i = tid; i < 10240; i += 512) dst[i] = sA[i];
    if (tid < 20) cntpart[(size_t)ch * 1280 + b * 20 + tid] = scnt[tid];
}

// ---------------- K2: fixed-order reduce ----------------
__global__ __launch_bounds__(256) void reduce_k(const float* __restrict__ Apart,
                                                const float* __restrict__ cntpart,
                                                float* __restrict__ A,
                                                float* __restrict__ cnt) {
    int i = blockIdx.x * 256 + threadIdx.x;
    if (i < 655360) {
        float s = 0.f;
#pragma unroll
        for (int p = 0; p < 8; p++) s += Apart[(size_t)p * 655360 + i];
        A[i] = s;
    }
    if (i < 1280) {
        float s = 0.f;
#pragma unroll
        for (int p = 0; p < 8; p++) s += cntpart[p * 1280 + i];
        cnt[i] = s;
    }
}

// ---------------- tiled fp32 GEMM 64x64x16 ----------------
// EPI 0: C0 = acc (+bias[c]); EPI 1: relu(acc + extra[r]*bias[c]);
// EPI 2: gelu(acc + bias[c]); EPI 3: N=1024 split -> mu / 0.01+0.99*softplus
template <int EPI, bool BT>
__global__ __launch_bounds__(256) void gemm_k(const float* __restrict__ A,
                                              const float* __restrict__ B,
                                              const float* __restrict__ bias,
                                              const float* __restrict__ extra,
                                              float* __restrict__ C0,
                                              float* __restrict__ C1,
                                              int Mm, int Nn, int Kk) {
    __shared__ float As[16][65];
    __shared__ float Bs[16][65];
    const int tid = threadIdx.x;
    const int tx = tid & 15, ty = tid >> 4;
    const int row0 = blockIdx.y * 64, col0 = blockIdx.x * 64;
    float acc[4][4] = {};
    for (int k0 = 0; k0 < Kk; k0 += 16) {
#pragma unroll
        for (int l = 0; l < 4; l++) {
            int idx = tid + l * 256;
            { int mm = idx >> 4, kk = idx & 15;
              As[kk][mm] = A[(size_t)(row0 + mm) * Kk + k0 + kk]; }
            if (BT) { int nn = idx >> 4, kk = idx & 15;
                      Bs[kk][nn] = B[(size_t)(col0 + nn) * Kk + k0 + kk]; }
            else    { int kk = idx >> 6, nn = idx & 63;
                      Bs[kk][nn] = B[(size_t)(k0 + kk) * Nn + col0 + nn]; }
        }
        __syncthreads();
#pragma unroll
        for (int kk = 0; kk < 16; kk++) {
            float a[4], bb[4];
#pragma unroll
            for (int i = 0; i < 4; i++) a[i] = As[kk][ty * 4 + i];
#pragma unroll
            for (int j = 0; j < 4; j++) bb[j] = Bs[kk][tx * 4 + j];
#pragma unroll
            for (int i = 0; i < 4; i++)
#pragma unroll
                for (int j = 0; j < 4; j++) acc[i][j] = fmaf(a[i], bb[j], acc[i][j]);
        }
        __syncthreads();
    }
#pragma unroll
    for (int i = 0; i < 4; i++) {
        int r = row0 + ty * 4 + i;
#pragma unroll
        for (int j = 0; j < 4; j++) {
            int c = col0 + tx * 4 + j;
            float v = acc[i][j];
            if (EPI == 0) {
                if (bias) v += bias[c];
                C0[(size_t)r * Nn + c] = v;
            } else if (EPI == 1) {
                v += extra[r] * bias[c];
                C0[(size_t)r * Nn + c] = fmaxf(v, 0.f);
            } else if (EPI == 2) {
                v += bias[c];
                C0[(size_t)r * Nn + c] = gelu_f(v);
            } else {
                v += bias[c];
                if (c < 512) C0[(size_t)r * 512 + c] = v;
                else C1[(size_t)r * 512 + (c - 512)] = 0.01f + 0.99f * softplus_f(v);
            }
        }
    }
}

// ---------------- K6: z = mu + scale*eps  (PARTITIONABLE threefry) ----------------
// JAX >=0.4.36 default: bits[i] = o0 ^ o1 with counter (hi32(i), lo32(i)) = (0, i)
__global__ __launch_bounds__(256) void z_k(const float* __restrict__ mu,
                                           const float* __restrict__ sc,
                                           float* __restrict__ z) {
    const uint32_t N = 5242880u; // 8*64*20*512
    uint32_t t = blockIdx.x * 256u + threadIdx.x;
    if (t >= N) return;
    uint32_t o0, o1;
    threefry2x32(0u, 42u, 0u, t, o0, o1);
    uint32_t rem = t % 655360u;
    z[t] = mu[rem] + sc[rem] * bits_to_normal(o0 ^ o1);
}

// ---------------- K10: beta[r] = dot(bp, Wf[r,:]) ----------------
__global__ __launch_bounds__(256) void beta_k(const float* __restrict__ Wf,
                                              const float* __restrict__ bp,
                                              float* __restrict__ beta) {
    int wave = threadIdx.x >> 6, lane = threadIdx.x & 63;
    int r = blockIdx.x * 4 + wave;
    const float* w = Wf + (size_t)r * 512;
    float s = 0.f;
    for (int d = lane; d < 512; d += 64) s += bp[d] * w[d];
#pragma unroll
    for (int o = 32; o > 0; o >>= 1) s += __shfl_down(s, o, 64);
    if (lane == 0) beta[r] = s;
}

// ---------------- K11: logits ----------------
// logits[s,b,q,n] = sum_c x_query[b,q,c] * V[s,b,n,c] + beta[s,b,n]
__global__ __launch_bounds__(256) void logits2_k(const float* __restrict__ Xq,
                                                 const float* __restrict__ V,
                                                 const float* __restrict__ beta,
                                                 float* __restrict__ out) {
    __shared__ float Vs[20 * 512]; // 40 KB
    __shared__ float bs[20];
    const int b = blockIdx.x, s = blockIdx.y;
    const int tid = threadIdx.x;
    const float* Vsb = V + (size_t)(s * 64 + b) * 10240;
    for (int i = tid; i < 10240; i += 256) Vs[i] = Vsb[i];
    if (tid < 20) bs[tid] = beta[(size_t)(s * 64 + b) * 20 + tid];
    __syncthreads();
    const size_t ob = (size_t)(s * 64 + b) * 20000;
    for (int q = tid; q < 1000; q += 256) {
        const float4* xr = (const float4*)(Xq + ((size_t)b * 1000 + q) * 512);
        float acc[20];
#pragma unroll
        for (int n = 0; n < 20; n++) acc[n] = 0.f;
        for (int c4 = 0; c4 < 128; c4++) {
            float4 x = xr[c4];
#pragma unroll
            for (int n = 0; n < 20; n++) {
                const float* vp = &Vs[n * 512 + c4 * 4];
                acc[n] = fmaf(x.x, vp[0], acc[n]);
                acc[n] = fmaf(x.y, vp[1], acc[n]);
                acc[n] = fmaf(x.z, vp[2], acc[n]);
                acc[n] = fmaf(x.w, vp[3], acc[n]);
            }
        }
#pragma unroll
        for (int n = 0; n < 20; n++) out[ob + (size_t)q * 20 + n] = acc[n] + bs[n];
    }
}

extern "C" void kernel_launch(void* const* d_in, const int* in_sizes, int n_in,
                              void* d_out, int out_size, void* d_ws, size_t ws_size,
                              hipStream_t stream) {
    const float* x_context = (const float*)d_in[0];
    const int*   y_context = (const int*)d_in[1];
    const float* x_query   = (const float*)d_in[2];
    const float* Wp  = (const float*)d_in[3];
    const float* bp  = (const float*)d_in[4];
    const float* Wa1 = (const float*)d_in[5];
    const float* ba1 = (const float*)d_in[6];
    const float* Wa2 = (const float*)d_in[7];
    const float* ba2 = (const float*)d_in[8];
    const float* Wd1 = (const float*)d_in[9];
    const float* bd1 = (const float*)d_in[10];
    const float* Wd2 = (const float*)d_in[11];
    const float* bd2 = (const float*)d_in[12];

    float* out    = (float*)d_out;
    float* logits = out;                  // 10,240,000
    float* z      = out + 10240000;       // 5,242,880
    float* mu     = out + 15482880;       // 655,360
    float* sc     = out + 16138240;       // 655,360
    float* Wf     = out;                  // scratch in logits region -- overwritten by logits last

    // workspace (floats), total 7,220,480 floats = 27.5 MiB
    float* ws   = (float*)d_ws;
    float* A    = ws;                    // 655,360
    float* comb = A + 655360;            // 655,360
    float* h    = comb + 655360;         // 655,360
    float* cnt  = h + 655360;            // 1,280
    float* beta = cnt + 1280;            // 10,240
    float* big  = beta + 10240;          // 5,242,880 : Apart -> Wg -> V (disjoint lifetimes)

    // 1-2) scatter + deterministic reduce -> A (1280,512), cnt (1280)
    scatter_k<<<dim3(64, 8), 512, 0, stream>>>(x_context, y_context, big /*Apart*/, beta /*cntpart*/);
    reduce_k<<<dim3(2560), 256, 0, stream>>>(big, beta, A, cnt);
    // 3) combined = relu(A@Wp + cnt*bp)
    gemm_k<1, false><<<dim3(8, 20), 256, 0, stream>>>(A, Wp, bp, cnt, comb, nullptr, 1280, 512, 512);
    // 4) h = gelu(comb@Wa1 + ba1)
    gemm_k<2, false><<<dim3(8, 20), 256, 0, stream>>>(comb, Wa1, ba1, nullptr, h, nullptr, 1280, 512, 512);
    // 5) stats = h@Wa2 + ba2 -> mu, scale
    gemm_k<3, false><<<dim3(16, 20), 256, 0, stream>>>(h, Wa2, ba2, nullptr, mu, sc, 1280, 1024, 512);
    // 6) z = mu + scale*eps (partitionable threefry)
    z_k<<<dim3(20480), 256, 0, stream>>>(mu, sc, z);
    // 7) Wg = gelu(z@Wd1 + bd1)  (in big; Apart dead)
    gemm_k<2, false><<<dim3(8, 160), 256, 0, stream>>>(z, Wd1, bd1, nullptr, big /*Wg*/, nullptr, 10240, 512, 512);
    // 8) Wf = Wg@Wd2 + bd2       (into d_out logits region)
    gemm_k<0, false><<<dim3(8, 160), 256, 0, stream>>>(big, Wd2, bd2, nullptr, Wf, nullptr, 10240, 512, 512);
    // 9) V = Wf @ Wp^T           (into big; Wg dead)
    gemm_k<0, true><<<dim3(8, 160), 256, 0, stream>>>(Wf, Wp, nullptr, nullptr, big /*V*/, nullptr, 10240, 512, 512);
    // 10) beta[r] = dot(bp, Wf[r,:])
    beta_k<<<dim3(2560), 256, 0, stream>>>(Wf, bp, beta);
    // 11) logits (overwrites Wf region; reads only V/beta/x_query)
    logits2_k<<<dim3(64, 8), 256, 0, stream>>>(x_query, big /*V*/, beta, logits);
}

// Round 4
// 823.498 us; speedup vs baseline: 1.1489x; 1.1489x over previous
//
#include <hip/hip_runtime.h>
#include <hip/hip_bf16.h>
#include <stdint.h>

// Sizes: BS=64, M=1000, CLIP=512, D=512, N_WAYS=20, N_Z=8
// out = [logits (8,64,1000,20) | z (8,64,20,512) | mu (64,20,512) | scale (64,20,512)]

__device__ __forceinline__ float gelu_f(float x) {
    return 0.5f * x * (1.0f + erff(x * 0.70710678118654752440f));
}
__device__ __forceinline__ float softplus_f(float x) {
    return fmaxf(x, 0.0f) + log1pf(expf(-fabsf(x)));
}

// ---------------- threefry2x32 ----------------
__device__ __forceinline__ void threefry2x32(uint32_t k0, uint32_t k1,
                                             uint32_t x0, uint32_t x1,
                                             uint32_t& o0, uint32_t& o1) {
    uint32_t ks[3] = {k0, k1, k0 ^ k1 ^ 0x1BD11BDAu};
    x0 += ks[0]; x1 += ks[1];
    const uint32_t rot[8] = {13,15,26,6,17,29,16,24};
#pragma unroll
    for (int i = 0; i < 5; i++) {
#pragma unroll
        for (int j = 0; j < 4; j++) {
            uint32_t r = rot[(i & 1) * 4 + j];
            x0 += x1;
            x1 = (x1 << r) | (x1 >> (32 - r));
            x1 ^= x0;
        }
        x0 += ks[(i + 1) % 3];
        x1 += ks[(i + 2) % 3] + (uint32_t)(i + 1);
    }
    o0 = x0; o1 = x1;
}

__device__ __forceinline__ float bits_to_normal(uint32_t b) {
    float f = __uint_as_float((b >> 9) | 0x3F800000u) - 1.0f;
    const float lo = __uint_as_float(0xBF7FFFFFu); // nextafter(-1,0)
    float u = fmaxf(lo, f * 2.0f + lo);
    return 1.41421356237309504880f * erfinvf(u);
}

// ---------------- K1: class scatter partials (deterministic) ----------------
__global__ __launch_bounds__(512) void scatter_k(const float* __restrict__ xc,
                                                 const int* __restrict__ y,
                                                 float* __restrict__ Apart,
                                                 float* __restrict__ cntpart) {
    __shared__ float sA[20 * 512];
    __shared__ float scnt[20];
    const int b = blockIdx.x, ch = blockIdx.y;
    const int tid = threadIdx.x;
    for (int i = tid; i < 20 * 512; i += 512) sA[i] = 0.f;
    if (tid < 20) scnt[tid] = 0.f;
    __syncthreads();
    const int m0 = ch * 125, m1 = m0 + 125;
    for (int m = m0; m < m1; m++) {
        int cls = y[b * 1000 + m];
        sA[cls * 512 + tid] += xc[((size_t)b * 1000 + m) * 512 + tid];
        if (tid == 0) scnt[cls] += 1.f;
    }
    __syncthreads();
    float* dst = Apart + (size_t)ch * 655360 + (size_t)b * 10240;
    for (int i = tid; i < 10240; i += 512) dst[i] = sA[i];
    if (tid < 20) cntpart[(size_t)ch * 1280 + b * 20 + tid] = scnt[tid];
}

// ---------------- K2: fixed-order reduce ----------------
__global__ __launch_bounds__(256) void reduce_k(const float* __restrict__ Apart,
                                                const float* __restrict__ cntpart,
                                                float* __restrict__ A,
                                                float* __restrict__ cnt) {
    int i = blockIdx.x * 256 + threadIdx.x;
    if (i < 655360) {
        float s = 0.f;
#pragma unroll
        for (int p = 0; p < 8; p++) s += Apart[(size_t)p * 655360 + i];
        A[i] = s;
    }
    if (i < 1280) {
        float s = 0.f;
#pragma unroll
        for (int p = 0; p < 8; p++) s += cntpart[p * 1280 + i];
        cnt[i] = s;
    }
}

// ---------------- tiled fp32 GEMM 64x64x16 (small M) ----------------
// EPI 0: C0 = acc (+bias[c]); EPI 1: relu(acc + extra[r]*bias[c]);
// EPI 2: gelu(acc + bias[c]); EPI 3: N=1024 split -> mu / 0.01+0.99*softplus
template <int EPI, bool BT>
__global__ __launch_bounds__(256) void gemm_k(const float* __restrict__ A,
                                              const float* __restrict__ B,
                                              const float* __restrict__ bias,
                                              const float* __restrict__ extra,
                                              float* __restrict__ C0,
                                              float* __restrict__ C1,
                                              int Mm, int Nn, int Kk) {
    __shared__ float As[16][65];
    __shared__ float Bs[16][65];
    const int tid = threadIdx.x;
    const int tx = tid & 15, ty = tid >> 4;
    const int row0 = blockIdx.y * 64, col0 = blockIdx.x * 64;
    float acc[4][4] = {};
    for (int k0 = 0; k0 < Kk; k0 += 16) {
#pragma unroll
        for (int l = 0; l < 4; l++) {
            int idx = tid + l * 256;
            { int mm = idx >> 4, kk = idx & 15;
              As[kk][mm] = A[(size_t)(row0 + mm) * Kk + k0 + kk]; }
            if (BT) { int nn = idx >> 4, kk = idx & 15;
                      Bs[kk][nn] = B[(size_t)(col0 + nn) * Kk + k0 + kk]; }
            else    { int kk = idx >> 6, nn = idx & 63;
                      Bs[kk][nn] = B[(size_t)(k0 + kk) * Nn + col0 + nn]; }
        }
        __syncthreads();
#pragma unroll
        for (int kk = 0; kk < 16; kk++) {
            float a[4], bb[4];
#pragma unroll
            for (int i = 0; i < 4; i++) a[i] = As[kk][ty * 4 + i];
#pragma unroll
            for (int j = 0; j < 4; j++) bb[j] = Bs[kk][tx * 4 + j];
#pragma unroll
            for (int i = 0; i < 4; i++)
#pragma unroll
                for (int j = 0; j < 4; j++) acc[i][j] = fmaf(a[i], bb[j], acc[i][j]);
        }
        __syncthreads();
    }
#pragma unroll
    for (int i = 0; i < 4; i++) {
        int r = row0 + ty * 4 + i;
#pragma unroll
        for (int j = 0; j < 4; j++) {
            int c = col0 + tx * 4 + j;
            float v = acc[i][j];
            if (EPI == 0) {
                if (bias) v += bias[c];
                C0[(size_t)r * Nn + c] = v;
            } else if (EPI == 1) {
                v += extra[r] * bias[c];
                C0[(size_t)r * Nn + c] = fmaxf(v, 0.f);
            } else if (EPI == 2) {
                v += bias[c];
                C0[(size_t)r * Nn + c] = gelu_f(v);
            } else {
                v += bias[c];
                if (c < 512) C0[(size_t)r * 512 + c] = v;
                else C1[(size_t)r * 512 + (c - 512)] = 0.01f + 0.99f * softplus_f(v);
            }
        }
    }
}

// ---------------- tiled fp32 GEMM 128x128x16, 8x8/thread (big M) ----------------
template <int EPI, bool BT>
__global__ __launch_bounds__(256) void gemm128(const float* __restrict__ A,
                                               const float* __restrict__ B,
                                               const float* __restrict__ bias,
                                               float* __restrict__ C0,
                                               int Nn, int Kk) {
    __shared__ float As[16][132];
    __shared__ float Bs[16][132];
    const int tid = threadIdx.x;
    const int tx = tid & 15, ty = tid >> 4;
    const int row0 = blockIdx.y * 128, col0 = blockIdx.x * 128;
    float acc[8][8] = {};
    for (int k0 = 0; k0 < Kk; k0 += 16) {
#pragma unroll
        for (int l = 0; l < 2; l++) {
            int f = tid + l * 256;
            int r = f >> 2, kq = (f & 3) * 4;
            float4 v = *(const float4*)&A[(size_t)(row0 + r) * Kk + k0 + kq];
            As[kq + 0][r] = v.x; As[kq + 1][r] = v.y;
            As[kq + 2][r] = v.z; As[kq + 3][r] = v.w;
        }
        if (BT) {
#pragma unroll
            for (int l = 0; l < 2; l++) {
                int f = tid + l * 256;
                int n = f >> 2, kq = (f & 3) * 4;
                float4 v = *(const float4*)&B[(size_t)(col0 + n) * Kk + k0 + kq];
                Bs[kq + 0][n] = v.x; Bs[kq + 1][n] = v.y;
                Bs[kq + 2][n] = v.z; Bs[kq + 3][n] = v.w;
            }
        } else {
#pragma unroll
            for (int l = 0; l < 2; l++) {
                int f = tid + l * 256;
                int kk = f >> 5, n4 = (f & 31) * 4;
                *(float4*)&Bs[kk][n4] = *(const float4*)&B[(size_t)(k0 + kk) * Nn + col0 + n4];
            }
        }
        __syncthreads();
#pragma unroll
        for (int kk = 0; kk < 16; kk++) {
            float4 a0 = *(const float4*)&As[kk][ty * 4];
            float4 a1 = *(const float4*)&As[kk][64 + ty * 4];
            float4 b0 = *(const float4*)&Bs[kk][tx * 4];
            float4 b1 = *(const float4*)&Bs[kk][64 + tx * 4];
            float a[8] = {a0.x, a0.y, a0.z, a0.w, a1.x, a1.y, a1.z, a1.w};
            float bb[8] = {b0.x, b0.y, b0.z, b0.w, b1.x, b1.y, b1.z, b1.w};
#pragma unroll
            for (int i = 0; i < 8; i++)
#pragma unroll
                for (int j = 0; j < 8; j++) acc[i][j] = fmaf(a[i], bb[j], acc[i][j]);
        }
        __syncthreads();
    }
#pragma unroll
    for (int i = 0; i < 8; i++) {
        int r = row0 + (i >> 2) * 64 + ty * 4 + (i & 3);
#pragma unroll
        for (int jq = 0; jq < 2; jq++) {
            int c = col0 + jq * 64 + tx * 4;
            float4 v;
            float t[4];
#pragma unroll
            for (int j = 0; j < 4; j++) {
                float x = acc[i][jq * 4 + j];
                if (bias) x += bias[c + j];
                if (EPI == 2) x = gelu_f(x);
                t[j] = x;
            }
            v.x = t[0]; v.y = t[1]; v.z = t[2]; v.w = t[3];
            *(float4*)&C0[(size_t)r * Nn + c] = v;
        }
    }
}

// ---------------- K6: z = mu + scale*eps (partitionable threefry) ----------------
__global__ __launch_bounds__(256) void z_k(const float* __restrict__ mu,
                                           const float* __restrict__ sc,
                                           float* __restrict__ z) {
    const uint32_t N = 5242880u; // 8*64*20*512
    uint32_t t = blockIdx.x * 256u + threadIdx.x;
    if (t >= N) return;
    uint32_t o0, o1;
    threefry2x32(0u, 42u, 0u, t, o0, o1);
    uint32_t rem = t % 655360u;
    z[t] = mu[rem] + sc[rem] * bits_to_normal(o0 ^ o1);
}

// ---------------- K10: beta[r] = dot(bp, Wf[r,:]) ----------------
__global__ __launch_bounds__(256) void beta_k(const float* __restrict__ Wf,
                                              const float* __restrict__ bp,
                                              float* __restrict__ beta) {
    int wave = threadIdx.x >> 6, lane = threadIdx.x & 63;
    int r = blockIdx.x * 4 + wave;
    const float* w = Wf + (size_t)r * 512;
    float s = 0.f;
    for (int d = lane; d < 512; d += 64) s += bp[d] * w[d];
#pragma unroll
    for (int o = 32; o > 0; o >>= 1) s += __shfl_down(s, o, 64);
    if (lane == 0) beta[r] = s;
}

// ---------------- K11: logits, 4 q-rows x 20 classes per thread ----------------
// logits[s,b,q,n] = sum_c x_query[b,q,c] * V[s,b,n,c] + beta[s,b,n]
__global__ __launch_bounds__(256) void logits3_k(const float* __restrict__ Xq,
                                                 const float* __restrict__ V,
                                                 const float* __restrict__ beta,
                                                 float* __restrict__ out) {
    __shared__ float Vs[20 * 512]; // 40 KB
    __shared__ float bs[20];
    const int b = blockIdx.x, s = blockIdx.y;
    const int tid = threadIdx.x;
    const float* Vsb = V + (size_t)(s * 64 + b) * 10240;
    for (int i = tid; i < 2560; i += 256)
        *(float4*)&Vs[i * 4] = *(const float4*)&Vsb[i * 4];
    if (tid < 20) bs[tid] = beta[(size_t)(s * 64 + b) * 20 + tid];
    __syncthreads();

    const float* xbase = Xq + (size_t)b * 1000 * 512;
    const float4* xr[4];
#pragma unroll
    for (int i = 0; i < 4; i++) {
        int q = tid + 256 * i; if (q > 999) q = 999;
        xr[i] = (const float4*)(xbase + (size_t)q * 512);
    }
    float acc[4][20] = {};
    for (int c4 = 0; c4 < 128; c4++) {
        float4 x0 = xr[0][c4], x1 = xr[1][c4], x2 = xr[2][c4], x3 = xr[3][c4];
#pragma unroll
        for (int n = 0; n < 20; n++) {
            float4 v = *(const float4*)&Vs[n * 512 + c4 * 4];
            acc[0][n] = fmaf(x0.x, v.x, fmaf(x0.y, v.y, fmaf(x0.z, v.z, fmaf(x0.w, v.w, acc[0][n]))));
            acc[1][n] = fmaf(x1.x, v.x, fmaf(x1.y, v.y, fmaf(x1.z, v.z, fmaf(x1.w, v.w, acc[1][n]))));
            acc[2][n] = fmaf(x2.x, v.x, fmaf(x2.y, v.y, fmaf(x2.z, v.z, fmaf(x2.w, v.w, acc[2][n]))));
            acc[3][n] = fmaf(x3.x, v.x, fmaf(x3.y, v.y, fmaf(x3.z, v.z, fmaf(x3.w, v.w, acc[3][n]))));
        }
    }
    size_t ob = (size_t)(s * 64 + b) * 20000;
#pragma unroll
    for (int i = 0; i < 4; i++) {
        int q = tid + 256 * i;
        if (q < 1000) {
#pragma unroll
            for (int n = 0; n < 20; n++)
                out[ob + (size_t)q * 20 + n] = acc[i][n] + bs[n];
        }
    }
}

extern "C" void kernel_launch(void* const* d_in, const int* in_sizes, int n_in,
                              void* d_out, int out_size, void* d_ws, size_t ws_size,
                              hipStream_t stream) {
    const float* x_context = (const float*)d_in[0];
    const int*   y_context = (const int*)d_in[1];
    const float* x_query   = (const float*)d_in[2];
    const float* Wp  = (const float*)d_in[3];
    const float* bp  = (const float*)d_in[4];
    const float* Wa1 = (const float*)d_in[5];
    const float* ba1 = (const float*)d_in[6];
    const float* Wa2 = (const float*)d_in[7];
    const float* ba2 = (const float*)d_in[8];
    const float* Wd1 = (const float*)d_in[9];
    const float* bd1 = (const float*)d_in[10];
    const float* Wd2 = (const float*)d_in[11];
    const float* bd2 = (const float*)d_in[12];

    float* out    = (float*)d_out;
    float* logits = out;                  // 10,240,000
    float* z      = out + 10240000;       // 5,242,880
    float* mu     = out + 15482880;       // 655,360
    float* sc     = out + 16138240;       // 655,360
    float* Wf     = out;                  // scratch in logits region -- overwritten last

    // workspace (floats), total 7,220,480 floats = 27.5 MiB
    float* ws   = (float*)d_ws;
    float* A    = ws;                    // 655,360
    float* comb = A + 655360;            // 655,360
    float* h    = comb + 655360;         // 655,360
    float* cnt  = h + 655360;            // 1,280
    float* beta = cnt + 1280;            // 10,240
    float* big  = beta + 10240;          // 5,242,880 : Apart -> Wg -> V (disjoint lifetimes)

    // 1-2) scatter + deterministic reduce -> A (1280,512), cnt (1280)
    scatter_k<<<dim3(64, 8), 512, 0, stream>>>(x_context, y_context, big /*Apart*/, beta /*cntpart*/);
    reduce_k<<<dim3(2560), 256, 0, stream>>>(big, beta, A, cnt);
    // 3) combined = relu(A@Wp + cnt*bp)
    gemm_k<1, false><<<dim3(8, 20), 256, 0, stream>>>(A, Wp, bp, cnt, comb, nullptr, 1280, 512, 512);
    // 4) h = gelu(comb@Wa1 + ba1)
    gemm_k<2, false><<<dim3(8, 20), 256, 0, stream>>>(comb, Wa1, ba1, nullptr, h, nullptr, 1280, 512, 512);
    // 5) stats = h@Wa2 + ba2 -> mu, scale
    gemm_k<3, false><<<dim3(16, 20), 256, 0, stream>>>(h, Wa2, ba2, nullptr, mu, sc, 1280, 1024, 512);
    // 6) z = mu + scale*eps
    z_k<<<dim3(20480), 256, 0, stream>>>(mu, sc, z);
    // 7) Wg = gelu(z@Wd1 + bd1)  (in big; Apart dead)
    gemm128<2, false><<<dim3(4, 80), 256, 0, stream>>>(z, Wd1, bd1, big /*Wg*/, 512, 512);
    // 8) Wf = Wg@Wd2 + bd2       (into d_out logits region)
    gemm128<0, false><<<dim3(4, 80), 256, 0, stream>>>(big, Wd2, bd2, Wf, 512, 512);
    // 9) V = Wf @ Wp^T           (into big; Wg dead)
    gemm128<0, true><<<dim3(4, 80), 256, 0, stream>>>(Wf, Wp, nullptr, big /*V*/, 512, 512);
    // 10) beta[r] = dot(bp, Wf[r,:])
    beta_k<<<dim3(2560), 256, 0, stream>>>(Wf, bp, beta);
    // 11) logits (overwrites Wf region; reads only V/beta/x_query)
    logits3_k<<<dim3(64, 8), 256, 0, stream>>>(x_query, big /*V*/, beta, logits);
}

// Round 5
// 728.293 us; speedup vs baseline: 1.2990x; 1.1307x over previous
//
#include <hip/hip_runtime.h>
#include <hip/hip_bf16.h>
#include <stdint.h>

// Sizes: BS=64, M=1000, CLIP=512, D=512, N_WAYS=20, N_Z=8
// out = [logits (8,64,1000,20) | z (8,64,20,512) | mu (64,20,512) | scale (64,20,512)]

typedef __attribute__((ext_vector_type(8))) short short8;
typedef __attribute__((ext_vector_type(4))) float f32x4;

__device__ __forceinline__ float gelu_f(float x) {
    return 0.5f * x * (1.0f + erff(x * 0.70710678118654752440f));
}
__device__ __forceinline__ float softplus_f(float x) {
    return fmaxf(x, 0.0f) + log1pf(expf(-fabsf(x)));
}
__device__ __forceinline__ uint32_t f2bf(float f) {  // RNE fp32->bf16
    union { float f; uint32_t u; } v; v.f = f;
    return (v.u + 0x7FFFu + ((v.u >> 16) & 1u)) >> 16;
}
__device__ __forceinline__ uint32_t packbf2(float a, float b) {
    return f2bf(a) | (f2bf(b) << 16);
}

// ---------------- threefry2x32 ----------------
__device__ __forceinline__ void threefry2x32(uint32_t k0, uint32_t k1,
                                             uint32_t x0, uint32_t x1,
                                             uint32_t& o0, uint32_t& o1) {
    uint32_t ks[3] = {k0, k1, k0 ^ k1 ^ 0x1BD11BDAu};
    x0 += ks[0]; x1 += ks[1];
    const uint32_t rot[8] = {13,15,26,6,17,29,16,24};
#pragma unroll
    for (int i = 0; i < 5; i++) {
#pragma unroll
        for (int j = 0; j < 4; j++) {
            uint32_t r = rot[(i & 1) * 4 + j];
            x0 += x1;
            x1 = (x1 << r) | (x1 >> (32 - r));
            x1 ^= x0;
        }
        x0 += ks[(i + 1) % 3];
        x1 += ks[(i + 2) % 3] + (uint32_t)(i + 1);
    }
    o0 = x0; o1 = x1;
}

__device__ __forceinline__ float bits_to_normal(uint32_t b) {
    float f = __uint_as_float((b >> 9) | 0x3F800000u) - 1.0f;
    const float lo = __uint_as_float(0xBF7FFFFFu); // nextafter(-1,0)
    float u = fmaxf(lo, f * 2.0f + lo);
    return 1.41421356237309504880f * erfinvf(u);
}

// ---------------- K1: class scatter partials (deterministic) ----------------
__global__ __launch_bounds__(512) void scatter_k(const float* __restrict__ xc,
                                                 const int* __restrict__ y,
                                                 float* __restrict__ Apart,
                                                 float* __restrict__ cntpart) {
    __shared__ float sA[20 * 512];
    __shared__ float scnt[20];
    const int b = blockIdx.x, ch = blockIdx.y;
    const int tid = threadIdx.x;
    for (int i = tid; i < 20 * 512; i += 512) sA[i] = 0.f;
    if (tid < 20) scnt[tid] = 0.f;
    __syncthreads();
    const int m0 = ch * 125, m1 = m0 + 125;
    for (int m = m0; m < m1; m++) {
        int cls = y[b * 1000 + m];
        sA[cls * 512 + tid] += xc[((size_t)b * 1000 + m) * 512 + tid];
        if (tid == 0) scnt[cls] += 1.f;
    }
    __syncthreads();
    float* dst = Apart + (size_t)ch * 655360 + (size_t)b * 10240;
    for (int i = tid; i < 10240; i += 512) dst[i] = sA[i];
    if (tid < 20) cntpart[(size_t)ch * 1280 + b * 20 + tid] = scnt[tid];
}

// ---------------- K2: fixed-order reduce ----------------
__global__ __launch_bounds__(256) void reduce_k(const float* __restrict__ Apart,
                                                const float* __restrict__ cntpart,
                                                float* __restrict__ A,
                                                float* __restrict__ cnt) {
    int i = blockIdx.x * 256 + threadIdx.x;
    if (i < 655360) {
        float s = 0.f;
#pragma unroll
        for (int p = 0; p < 8; p++) s += Apart[(size_t)p * 655360 + i];
        A[i] = s;
    }
    if (i < 1280) {
        float s = 0.f;
#pragma unroll
        for (int p = 0; p < 8; p++) s += cntpart[p * 1280 + i];
        cnt[i] = s;
    }
}

// ---------------- tiled fp32 GEMM 64x64x16 (small M) ----------------
template <int EPI, bool BT>
__global__ __launch_bounds__(256) void gemm_k(const float* __restrict__ A,
                                              const float* __restrict__ B,
                                              const float* __restrict__ bias,
                                              const float* __restrict__ extra,
                                              float* __restrict__ C0,
                                              float* __restrict__ C1,
                                              int Mm, int Nn, int Kk) {
    __shared__ float As[16][65];
    __shared__ float Bs[16][65];
    const int tid = threadIdx.x;
    const int tx = tid & 15, ty = tid >> 4;
    const int row0 = blockIdx.y * 64, col0 = blockIdx.x * 64;
    float acc[4][4] = {};
    for (int k0 = 0; k0 < Kk; k0 += 16) {
#pragma unroll
        for (int l = 0; l < 4; l++) {
            int idx = tid + l * 256;
            { int mm = idx >> 4, kk = idx & 15;
              As[kk][mm] = A[(size_t)(row0 + mm) * Kk + k0 + kk]; }
            if (BT) { int nn = idx >> 4, kk = idx & 15;
                      Bs[kk][nn] = B[(size_t)(col0 + nn) * Kk + k0 + kk]; }
            else    { int kk = idx >> 6, nn = idx & 63;
                      Bs[kk][nn] = B[(size_t)(k0 + kk) * Nn + col0 + nn]; }
        }
        __syncthreads();
#pragma unroll
        for (int kk = 0; kk < 16; kk++) {
            float a[4], bb[4];
#pragma unroll
            for (int i = 0; i < 4; i++) a[i] = As[kk][ty * 4 + i];
#pragma unroll
            for (int j = 0; j < 4; j++) bb[j] = Bs[kk][tx * 4 + j];
#pragma unroll
            for (int i = 0; i < 4; i++)
#pragma unroll
                for (int j = 0; j < 4; j++) acc[i][j] = fmaf(a[i], bb[j], acc[i][j]);
        }
        __syncthreads();
    }
#pragma unroll
    for (int i = 0; i < 4; i++) {
        int r = row0 + ty * 4 + i;
#pragma unroll
        for (int j = 0; j < 4; j++) {
            int c = col0 + tx * 4 + j;
            float v = acc[i][j];
            if (EPI == 0) {
                if (bias) v += bias[c];
                C0[(size_t)r * Nn + c] = v;
            } else if (EPI == 1) {
                v += extra[r] * bias[c];
                C0[(size_t)r * Nn + c] = fmaxf(v, 0.f);
            } else if (EPI == 2) {
                v += bias[c];
                C0[(size_t)r * Nn + c] = gelu_f(v);
            } else {
                v += bias[c];
                if (c < 512) C0[(size_t)r * 512 + c] = v;
                else C1[(size_t)r * 512 + (c - 512)] = 0.01f + 0.99f * softplus_f(v);
            }
        }
    }
}

// ---------------- tiled fp32 GEMM 128x128x16, 8x8/thread (big M) ----------------
template <int EPI, bool BT>
__global__ __launch_bounds__(256) void gemm128(const float* __restrict__ A,
                                               const float* __restrict__ B,
                                               const float* __restrict__ bias,
                                               float* __restrict__ C0,
                                               int Nn, int Kk) {
    __shared__ float As[16][132];
    __shared__ float Bs[16][132];
    const int tid = threadIdx.x;
    const int tx = tid & 15, ty = tid >> 4;
    const int row0 = blockIdx.y * 128, col0 = blockIdx.x * 128;
    float acc[8][8] = {};
    for (int k0 = 0; k0 < Kk; k0 += 16) {
#pragma unroll
        for (int l = 0; l < 2; l++) {
            int f = tid + l * 256;
            int r = f >> 2, kq = (f & 3) * 4;
            float4 v = *(const float4*)&A[(size_t)(row0 + r) * Kk + k0 + kq];
            As[kq + 0][r] = v.x; As[kq + 1][r] = v.y;
            As[kq + 2][r] = v.z; As[kq + 3][r] = v.w;
        }
        if (BT) {
#pragma unroll
            for (int l = 0; l < 2; l++) {
                int f = tid + l * 256;
                int n = f >> 2, kq = (f & 3) * 4;
                float4 v = *(const float4*)&B[(size_t)(col0 + n) * Kk + k0 + kq];
                Bs[kq + 0][n] = v.x; Bs[kq + 1][n] = v.y;
                Bs[kq + 2][n] = v.z; Bs[kq + 3][n] = v.w;
            }
        } else {
#pragma unroll
            for (int l = 0; l < 2; l++) {
                int f = tid + l * 256;
                int kk = f >> 5, n4 = (f & 31) * 4;
                *(float4*)&Bs[kk][n4] = *(const float4*)&B[(size_t)(k0 + kk) * Nn + col0 + n4];
            }
        }
        __syncthreads();
#pragma unroll
        for (int kk = 0; kk < 16; kk++) {
            float4 a0 = *(const float4*)&As[kk][ty * 4];
            float4 a1 = *(const float4*)&As[kk][64 + ty * 4];
            float4 b0 = *(const float4*)&Bs[kk][tx * 4];
            float4 b1 = *(const float4*)&Bs[kk][64 + tx * 4];
            float a[8] = {a0.x, a0.y, a0.z, a0.w, a1.x, a1.y, a1.z, a1.w};
            float bb[8] = {b0.x, b0.y, b0.z, b0.w, b1.x, b1.y, b1.z, b1.w};
#pragma unroll
            for (int i = 0; i < 8; i++)
#pragma unroll
                for (int j = 0; j < 8; j++) acc[i][j] = fmaf(a[i], bb[j], acc[i][j]);
        }
        __syncthreads();
    }
#pragma unroll
    for (int i = 0; i < 8; i++) {
        int r = row0 + (i >> 2) * 64 + ty * 4 + (i & 3);
#pragma unroll
        for (int jq = 0; jq < 2; jq++) {
            int c = col0 + jq * 64 + tx * 4;
            float4 v;
            float t[4];
#pragma unroll
            for (int j = 0; j < 4; j++) {
                float x = acc[i][jq * 4 + j];
                if (bias) x += bias[c + j];
                if (EPI == 2) x = gelu_f(x);
                t[j] = x;
            }
            v.x = t[0]; v.y = t[1]; v.z = t[2]; v.w = t[3];
            *(float4*)&C0[(size_t)r * Nn + c] = v;
        }
    }
}

// ---------------- K6: z = mu + scale*eps (partitionable threefry) ----------------
__global__ __launch_bounds__(256) void z_k(const float* __restrict__ mu,
                                           const float* __restrict__ sc,
                                           float* __restrict__ z) {
    const uint32_t N = 5242880u; // 8*64*20*512
    uint32_t t = blockIdx.x * 256u + threadIdx.x;
    if (t >= N) return;
    uint32_t o0, o1;
    threefry2x32(0u, 42u, 0u, t, o0, o1);
    uint32_t rem = t % 655360u;
    z[t] = mu[rem] + sc[rem] * bits_to_normal(o0 ^ o1);
}

// ---------------- K10: beta[r] = dot(bp, Wf[r,:]) ----------------
__global__ __launch_bounds__(256) void beta_k(const float* __restrict__ Wf,
                                              const float* __restrict__ bp,
                                              float* __restrict__ beta) {
    int wave = threadIdx.x >> 6, lane = threadIdx.x & 63;
    int r = blockIdx.x * 4 + wave;
    const float* w = Wf + (size_t)r * 512;
    float s = 0.f;
    for (int d = lane; d < 512; d += 64) s += bp[d] * w[d];
#pragma unroll
    for (int o = 32; o > 0; o >>= 1) s += __shfl_down(s, o, 64);
    if (lane == 0) beta[r] = s;
}

// ---------------- K11: logits via bf16 MFMA ----------------
// per (s,b): C[1000x20] = Xq[b] (1000x512) @ V[s,b]^T (512x20) + beta
// mfma_f32_16x16x32_bf16: A row=lane&15, k=8*(lane>>4)+e; B n=lane&15, same k;
// D col=lane&15, row=(lane>>4)*4+reg  [m89-verified]
__global__ __launch_bounds__(256) void logits_mfma_k(const float* __restrict__ Xq,
                                                     const float* __restrict__ V,
                                                     const float* __restrict__ beta,
                                                     float* __restrict__ out) {
    __shared__ unsigned short Vs[32 * 512];  // bf16, 32 KB, XOR-swizzled rows (20 valid + 12 zero)
    __shared__ unsigned short Xs[128 * 64];  // bf16, 16 KB, XOR-swizzled
    __shared__ float bs[32];
    const int b = blockIdx.x, s = blockIdx.y;
    const int tid = threadIdx.x;
    const int lane = tid & 63, w = tid >> 6;

    // stage V -> Vs (bf16, swizzled); rows 20..31 zero
    const float* Vsb = V + (size_t)(s * 64 + b) * 10240;
    for (int idx = tid; idx < 32 * 256; idx += 256) {
        int n = idx >> 8, kp = idx & 255;  // k = 2*kp
        uint32_t val = 0;
        if (n < 20) val = packbf2(Vsb[n * 512 + kp * 2], Vsb[n * 512 + kp * 2 + 1]);
        int byte = (kp * 4) ^ ((n & 7) << 4);
        *(uint32_t*)((char*)Vs + n * 1024 + byte) = val;
    }
    if (tid < 32) bs[tid] = (tid < 20) ? beta[(size_t)(s * 64 + b) * 20 + tid] : 0.f;

    const float* xbase = Xq + (size_t)b * 1000 * 512;
    const size_t ob = (size_t)(s * 64 + b) * 20000;

    for (int q0 = 0; q0 < 1024; q0 += 128) {
        f32x4 acc[2][2] = {};
        for (int k0 = 0; k0 < 512; k0 += 64) {
            __syncthreads();  // previous compute done; V staging done (first iter)
            // stage Xs[128][64] bf16 swizzled; 2 threads/row, 32 floats each
            {
                int row = tid >> 1, ch = (tid & 1) * 32;
                int q = q0 + row; if (q > 999) q = 999;
                const float* xr = xbase + (size_t)q * 512 + k0 + ch;
                char* dst = (char*)Xs + row * 128;
                int swz = (row & 7) << 4;
#pragma unroll
                for (int j = 0; j < 8; j++) {
                    float4 v = *(const float4*)(xr + j * 4);
                    uint64_t u = (uint64_t)packbf2(v.x, v.y) |
                                 ((uint64_t)packbf2(v.z, v.w) << 32);
                    int byte = ((ch + j * 4) * 2) ^ swz;
                    *(uint64_t*)(dst + byte) = u;
                }
            }
            __syncthreads();
#pragma unroll
            for (int kk = 0; kk < 64; kk += 32) {
                int r0 = w * 32 + (lane & 15);
                int r1 = r0 + 16;
                int kb = (kk + (lane >> 4) * 8) * 2;
                short8 a0 = *(const short8*)((const char*)Xs + r0 * 128 + (kb ^ ((r0 & 7) << 4)));
                short8 a1 = *(const short8*)((const char*)Xs + r1 * 128 + (kb ^ ((r1 & 7) << 4)));
                int n0 = lane & 15, n1 = n0 + 16;
                int kb2 = (k0 + kk + (lane >> 4) * 8) * 2;
                short8 b0 = *(const short8*)((const char*)Vs + n0 * 1024 + (kb2 ^ ((n0 & 7) << 4)));
                short8 b1 = *(const short8*)((const char*)Vs + n1 * 1024 + (kb2 ^ ((n1 & 7) << 4)));
                acc[0][0] = __builtin_amdgcn_mfma_f32_16x16x32_bf16(a0, b0, acc[0][0], 0, 0, 0);
                acc[0][1] = __builtin_amdgcn_mfma_f32_16x16x32_bf16(a0, b1, acc[0][1], 0, 0, 0);
                acc[1][0] = __builtin_amdgcn_mfma_f32_16x16x32_bf16(a1, b0, acc[1][0], 0, 0, 0);
                acc[1][1] = __builtin_amdgcn_mfma_f32_16x16x32_bf16(a1, b1, acc[1][1], 0, 0, 0);
            }
        }
        // store: q = q0 + w*32 + qs*16 + (lane>>4)*4 + r ; n = nf*16 + (lane&15)
#pragma unroll
        for (int qs = 0; qs < 2; qs++) {
#pragma unroll
            for (int nf = 0; nf < 2; nf++) {
                int n = nf * 16 + (lane & 15);
#pragma unroll
                for (int r = 0; r < 4; r++) {
                    int q = q0 + w * 32 + qs * 16 + (lane >> 4) * 4 + r;
                    if (q < 1000 && n < 20)
                        out[ob + (size_t)q * 20 + n] = acc[qs][nf][r] + bs[n];
                }
            }
        }
    }
}

extern "C" void kernel_launch(void* const* d_in, const int* in_sizes, int n_in,
                              void* d_out, int out_size, void* d_ws, size_t ws_size,
                              hipStream_t stream) {
    const float* x_context = (const float*)d_in[0];
    const int*   y_context = (const int*)d_in[1];
    const float* x_query   = (const float*)d_in[2];
    const float* Wp  = (const float*)d_in[3];
    const float* bp  = (const float*)d_in[4];
    const float* Wa1 = (const float*)d_in[5];
    const float* ba1 = (const float*)d_in[6];
    const float* Wa2 = (const float*)d_in[7];
    const float* ba2 = (const float*)d_in[8];
    const float* Wd1 = (const float*)d_in[9];
    const float* bd1 = (const float*)d_in[10];
    const float* Wd2 = (const float*)d_in[11];
    const float* bd2 = (const float*)d_in[12];

    float* out    = (float*)d_out;
    float* logits = out;                  // 10,240,000
    float* z      = out + 10240000;       // 5,242,880
    float* mu     = out + 15482880;       // 655,360
    float* sc     = out + 16138240;       // 655,360
    float* Wf     = out;                  // scratch in logits region -- overwritten last

    // workspace (floats), total 7,220,480 floats = 27.5 MiB
    float* ws   = (float*)d_ws;
    float* A    = ws;                    // 655,360
    float* comb = A + 655360;            // 655,360
    float* h    = comb + 655360;         // 655,360
    float* cnt  = h + 655360;            // 1,280
    float* beta = cnt + 1280;            // 10,240
    float* big  = beta + 10240;          // 5,242,880 : Apart -> Wg -> V (disjoint lifetimes)

    // 1-2) scatter + deterministic reduce -> A (1280,512), cnt (1280)
    scatter_k<<<dim3(64, 8), 512, 0, stream>>>(x_context, y_context, big /*Apart*/, beta /*cntpart*/);
    reduce_k<<<dim3(2560), 256, 0, stream>>>(big, beta, A, cnt);
    // 3) combined = relu(A@Wp + cnt*bp)
    gemm_k<1, false><<<dim3(8, 20), 256, 0, stream>>>(A, Wp, bp, cnt, comb, nullptr, 1280, 512, 512);
    // 4) h = gelu(comb@Wa1 + ba1)
    gemm_k<2, false><<<dim3(8, 20), 256, 0, stream>>>(comb, Wa1, ba1, nullptr, h, nullptr, 1280, 512, 512);
    // 5) stats = h@Wa2 + ba2 -> mu, scale
    gemm_k<3, false><<<dim3(16, 20), 256, 0, stream>>>(h, Wa2, ba2, nullptr, mu, sc, 1280, 1024, 512);
    // 6) z = mu + scale*eps
    z_k<<<dim3(20480), 256, 0, stream>>>(mu, sc, z);
    // 7) Wg = gelu(z@Wd1 + bd1)  (in big; Apart dead)
    gemm128<2, false><<<dim3(4, 80), 256, 0, stream>>>(z, Wd1, bd1, big /*Wg*/, 512, 512);
    // 8) Wf = Wg@Wd2 + bd2       (into d_out logits region)
    gemm128<0, false><<<dim3(4, 80), 256, 0, stream>>>(big, Wd2, bd2, Wf, 512, 512);
    // 9) V = Wf @ Wp^T           (into big; Wg dead)
    gemm128<0, true><<<dim3(4, 80), 256, 0, stream>>>(Wf, Wp, nullptr, big /*V*/, 512, 512);
    // 10) beta[r] = dot(bp, Wf[r,:])
    beta_k<<<dim3(2560), 256, 0, stream>>>(Wf, bp, beta);
    // 11) logits via MFMA (overwrites Wf region; reads only V/beta/x_query)
    logits_mfma_k<<<dim3(64, 8), 256, 0, stream>>>(x_query, big /*V*/, beta, logits);
}

// Round 6
// 440.105 us; speedup vs baseline: 2.1497x; 1.6548x over previous
//
#include <hip/hip_runtime.h>
#include <hip/hip_bf16.h>
#include <stdint.h>

// Sizes: BS=64, M=1000, CLIP=512, D=512, N_WAYS=20, N_Z=8
// out = [logits (8,64,1000,20) | z (8,64,20,512) | mu (64,20,512) | scale (64,20,512)]

typedef __attribute__((ext_vector_type(8))) short short8;
typedef __attribute__((ext_vector_type(4))) float f32x4;

__device__ __forceinline__ float gelu_f(float x) {
    return 0.5f * x * (1.0f + erff(x * 0.70710678118654752440f));
}
__device__ __forceinline__ float softplus_f(float x) {
    return fmaxf(x, 0.0f) + log1pf(expf(-fabsf(x)));
}
__device__ __forceinline__ uint32_t cvt2(float a, float b) {  // pack 2 bf16 (RNE)
    __hip_bfloat162 h;
    h.x = __float2bfloat16(a);
    h.y = __float2bfloat16(b);
    uint32_t u; __builtin_memcpy(&u, &h, 4); return u;
}
__device__ __forceinline__ unsigned short f2bfu(float f) {
    __hip_bfloat16 h = __float2bfloat16(f);
    unsigned short u; __builtin_memcpy(&u, &h, 2); return u;
}
__device__ __forceinline__ float bfu2f(unsigned short u) {
    uint32_t v = (uint32_t)u << 16; float f; __builtin_memcpy(&f, &v, 4); return f;
}

// ---------------- threefry2x32 (partitionable) ----------------
__device__ __forceinline__ void threefry2x32(uint32_t k0, uint32_t k1,
                                             uint32_t x0, uint32_t x1,
                                             uint32_t& o0, uint32_t& o1) {
    uint32_t ks[3] = {k0, k1, k0 ^ k1 ^ 0x1BD11BDAu};
    x0 += ks[0]; x1 += ks[1];
    const uint32_t rot[8] = {13,15,26,6,17,29,16,24};
#pragma unroll
    for (int i = 0; i < 5; i++) {
#pragma unroll
        for (int j = 0; j < 4; j++) {
            uint32_t r = rot[(i & 1) * 4 + j];
            x0 += x1;
            x1 = (x1 << r) | (x1 >> (32 - r));
            x1 ^= x0;
        }
        x0 += ks[(i + 1) % 3];
        x1 += ks[(i + 2) % 3] + (uint32_t)(i + 1);
    }
    o0 = x0; o1 = x1;
}

__device__ __forceinline__ float bits_to_normal(uint32_t b) {
    float f = __uint_as_float((b >> 9) | 0x3F800000u) - 1.0f;
    const float lo = __uint_as_float(0xBF7FFFFFu);
    float u = fmaxf(lo, f * 2.0f + lo);
    return 1.41421356237309504880f * erfinvf(u);
}

// ---------------- K1: class scatter partials ----------------
__global__ __launch_bounds__(512) void scatter_k(const float* __restrict__ xc,
                                                 const int* __restrict__ y,
                                                 float* __restrict__ Apart,
                                                 float* __restrict__ cntpart) {
    __shared__ float sA[20 * 512];
    __shared__ float scnt[20];
    const int b = blockIdx.x, ch = blockIdx.y;
    const int tid = threadIdx.x;
    for (int i = tid; i < 20 * 512; i += 512) sA[i] = 0.f;
    if (tid < 20) scnt[tid] = 0.f;
    __syncthreads();
    const int m0 = ch * 125, m1 = m0 + 125;
    for (int m = m0; m < m1; m++) {
        int cls = y[b * 1000 + m];
        sA[cls * 512 + tid] += xc[((size_t)b * 1000 + m) * 512 + tid];
        if (tid == 0) scnt[cls] += 1.f;
    }
    __syncthreads();
    float* dst = Apart + (size_t)ch * 655360 + (size_t)b * 10240;
    for (int i = tid; i < 10240; i += 512) dst[i] = sA[i];
    if (tid < 20) cntpart[(size_t)ch * 1280 + b * 20 + tid] = scnt[tid];
}

// ---------------- K2: fixed-order reduce ----------------
__global__ __launch_bounds__(256) void reduce_k(const float* __restrict__ Apart,
                                                const float* __restrict__ cntpart,
                                                float* __restrict__ A,
                                                float* __restrict__ cnt) {
    int i = blockIdx.x * 256 + threadIdx.x;
    if (i < 655360) {
        float s = 0.f;
#pragma unroll
        for (int p = 0; p < 8; p++) s += Apart[(size_t)p * 655360 + i];
        A[i] = s;
    }
    if (i < 1280) {
        float s = 0.f;
#pragma unroll
        for (int p = 0; p < 8; p++) s += cntpart[p * 1280 + i];
        cnt[i] = s;
    }
}

// ---------------- tiled fp32 GEMM 64x64x16 (small M=1280 chain) ----------------
template <int EPI, bool BT>
__global__ __launch_bounds__(256) void gemm_k(const float* __restrict__ A,
                                              const float* __restrict__ B,
                                              const float* __restrict__ bias,
                                              const float* __restrict__ extra,
                                              float* __restrict__ C0,
                                              float* __restrict__ C1,
                                              int Mm, int Nn, int Kk) {
    __shared__ float As[16][65];
    __shared__ float Bs[16][65];
    const int tid = threadIdx.x;
    const int tx = tid & 15, ty = tid >> 4;
    const int row0 = blockIdx.y * 64, col0 = blockIdx.x * 64;
    float acc[4][4] = {};
    for (int k0 = 0; k0 < Kk; k0 += 16) {
#pragma unroll
        for (int l = 0; l < 4; l++) {
            int idx = tid + l * 256;
            { int mm = idx >> 4, kk = idx & 15;
              As[kk][mm] = A[(size_t)(row0 + mm) * Kk + k0 + kk]; }
            if (BT) { int nn = idx >> 4, kk = idx & 15;
                      Bs[kk][nn] = B[(size_t)(col0 + nn) * Kk + k0 + kk]; }
            else    { int kk = idx >> 6, nn = idx & 63;
                      Bs[kk][nn] = B[(size_t)(k0 + kk) * Nn + col0 + nn]; }
        }
        __syncthreads();
#pragma unroll
        for (int kk = 0; kk < 16; kk++) {
            float a[4], bb[4];
#pragma unroll
            for (int i = 0; i < 4; i++) a[i] = As[kk][ty * 4 + i];
#pragma unroll
            for (int j = 0; j < 4; j++) bb[j] = Bs[kk][tx * 4 + j];
#pragma unroll
            for (int i = 0; i < 4; i++)
#pragma unroll
                for (int j = 0; j < 4; j++) acc[i][j] = fmaf(a[i], bb[j], acc[i][j]);
        }
        __syncthreads();
    }
#pragma unroll
    for (int i = 0; i < 4; i++) {
        int r = row0 + ty * 4 + i;
#pragma unroll
        for (int j = 0; j < 4; j++) {
            int c = col0 + tx * 4 + j;
            float v = acc[i][j];
            if (EPI == 0) {
                if (bias) v += bias[c];
                C0[(size_t)r * Nn + c] = v;
            } else if (EPI == 1) {
                v += extra[r] * bias[c];
                C0[(size_t)r * Nn + c] = fmaxf(v, 0.f);
            } else if (EPI == 2) {
                v += bias[c];
                C0[(size_t)r * Nn + c] = gelu_f(v);
            } else {
                v += bias[c];
                if (c < 512) C0[(size_t)r * 512 + c] = v;
                else C1[(size_t)r * 512 + (c - 512)] = 0.01f + 0.99f * softplus_f(v);
            }
        }
    }
}

// ---------------- z = mu + scale*eps ----------------
__global__ __launch_bounds__(256) void z_k(const float* __restrict__ mu,
                                           const float* __restrict__ sc,
                                           float* __restrict__ z) {
    const uint32_t N = 5242880u;
    uint32_t t = blockIdx.x * 256u + threadIdx.x;
    if (t >= N) return;
    uint32_t o0, o1;
    threefry2x32(0u, 42u, 0u, t, o0, o1);
    uint32_t rem = t % 655360u;
    z[t] = mu[rem] + sc[rem] * bits_to_normal(o0 ^ o1);
}

// ---------------- weight prep: transpose+bf16 (Wd1,Wd2) ----------------
__global__ __launch_bounds__(256) void wtrans_k(const float* __restrict__ W1,
                                                const float* __restrict__ W2,
                                                unsigned short* __restrict__ O1,
                                                unsigned short* __restrict__ O2) {
    __shared__ float T[64][65];
    const float* src = blockIdx.z ? W2 : W1;
    unsigned short* dst = blockIdx.z ? O2 : O1;
    const int r0 = blockIdx.y * 64, c0 = blockIdx.x * 64;
    const int tid = threadIdx.x;
    const int rr = tid >> 4, cc = (tid & 15) * 4;
#pragma unroll
    for (int l = 0; l < 4; l++) {
        int row = rr + l * 16;
        float4 v = *(const float4*)&src[(size_t)(r0 + row) * 512 + c0 + cc];
        T[row][cc] = v.x; T[row][cc+1] = v.y; T[row][cc+2] = v.z; T[row][cc+3] = v.w;
    }
    __syncthreads();
#pragma unroll
    for (int l = 0; l < 4; l++) {
        int n = rr + l * 16;
        uint2 u;
        u.x = cvt2(T[cc][n], T[cc+1][n]);
        u.y = cvt2(T[cc+2][n], T[cc+3][n]);
        *(uint2*)&dst[(size_t)(c0 + n) * 512 + r0 + cc] = u;
    }
}

// ---------------- weight prep: plain bf16 convert (Wp) ----------------
__global__ __launch_bounds__(256) void wconv_k(const float* __restrict__ in,
                                               unsigned short* __restrict__ o, int n2) {
    int i = blockIdx.x * 256 + threadIdx.x;
    if (i < n2) {
        float2 v = *(const float2*)&in[i * 2];
        *(uint32_t*)&o[i * 2] = cvt2(v.x, v.y);
    }
}

// ---------------- bf16 MFMA GEMM: C[M x 512] = act(A @ W + bias), out bf16 ----
// Bbf: [512 n][512 k] bf16 (row n = output column n). Tile 64x128x64, 4 waves.
template <int APACK, int ACT>
__global__ __launch_bounds__(256) void gemm_mfma_k(const void* __restrict__ Ap,
                                                   const unsigned short* __restrict__ Bbf,
                                                   const float* __restrict__ bias,
                                                   unsigned short* __restrict__ C) {
    __shared__ unsigned short As[64 * 64];    // 8 KB, row stride 128 B, XOR-swizzled
    __shared__ unsigned short Bs[128 * 64];   // 16 KB
    const int tid = threadIdx.x;
    const int lane = tid & 63, w = tid >> 6;
    const int row0 = blockIdx.y * 64, col0 = blockIdx.x * 128;
    f32x4 acc[4][2] = {};
    for (int k0 = 0; k0 < 512; k0 += 64) {
        {   // stage A (64 rows x 64 k)
            int row = tid >> 2, cs = (tid & 3) * 16;
            int swz = (row & 7) << 4;
            if (APACK) {
                const float* src = (const float*)Ap + (size_t)(row0 + row) * 512 + k0 + cs;
#pragma unroll
                for (int j = 0; j < 2; j++) {
                    float4 v0 = *(const float4*)(src + j * 8);
                    float4 v1 = *(const float4*)(src + j * 8 + 4);
                    uint4 u;
                    u.x = cvt2(v0.x, v0.y); u.y = cvt2(v0.z, v0.w);
                    u.z = cvt2(v1.x, v1.y); u.w = cvt2(v1.z, v1.w);
                    *(uint4*)((char*)As + row * 128 + (((cs + j * 8) * 2) ^ swz)) = u;
                }
            } else {
                const unsigned short* src = (const unsigned short*)Ap + (size_t)(row0 + row) * 512 + k0 + cs;
#pragma unroll
                for (int j = 0; j < 2; j++) {
                    uint4 u = *(const uint4*)(src + j * 8);
                    *(uint4*)((char*)As + row * 128 + (((cs + j * 8) * 2) ^ swz)) = u;
                }
            }
        }
        {   // stage B (128 rows x 64 k), bf16 direct
            int row = tid >> 1, cs = (tid & 1) * 32;
            int swz = (row & 7) << 4;
            const unsigned short* src = Bbf + (size_t)(col0 + row) * 512 + k0 + cs;
#pragma unroll
            for (int j = 0; j < 4; j++) {
                uint4 u = *(const uint4*)(src + j * 8);
                *(uint4*)((char*)Bs + row * 128 + (((cs + j * 8) * 2) ^ swz)) = u;
            }
        }
        __syncthreads();
#pragma unroll
        for (int ks = 0; ks < 2; ks++) {
            short8 a[4], bb[2];
#pragma unroll
            for (int mi = 0; mi < 4; mi++) {
                int r = mi * 16 + (lane & 15);
                a[mi] = *(const short8*)((const char*)As + r * 128 +
                          (((ks * 32 + (lane >> 4) * 8) * 2) ^ ((r & 7) << 4)));
            }
#pragma unroll
            for (int ni = 0; ni < 2; ni++) {
                int n = w * 32 + ni * 16 + (lane & 15);
                bb[ni] = *(const short8*)((const char*)Bs + n * 128 +
                          (((ks * 32 + (lane >> 4) * 8) * 2) ^ ((n & 7) << 4)));
            }
#pragma unroll
            for (int mi = 0; mi < 4; mi++)
#pragma unroll
                for (int ni = 0; ni < 2; ni++)
                    acc[mi][ni] = __builtin_amdgcn_mfma_f32_16x16x32_bf16(a[mi], bb[ni], acc[mi][ni], 0, 0, 0);
        }
        __syncthreads();
    }
#pragma unroll
    for (int mi = 0; mi < 4; mi++) {
#pragma unroll
        for (int ni = 0; ni < 2; ni++) {
            int c = col0 + w * 32 + ni * 16 + (lane & 15);
            float bv = bias ? bias[c] : 0.f;
#pragma unroll
            for (int j = 0; j < 4; j++) {
                int r = row0 + mi * 16 + (lane >> 4) * 4 + j;
                float v = acc[mi][ni][j] + bv;
                if (ACT) v = gelu_f(v);
                C[(size_t)r * 512 + c] = f2bfu(v);
            }
        }
    }
}

// ---------------- beta[r] = dot(bp, Wf_bf[r,:]) ----------------
__global__ __launch_bounds__(256) void beta_bf_k(const unsigned short* __restrict__ Wfb,
                                                 const float* __restrict__ bp,
                                                 float* __restrict__ beta) {
    int wave = threadIdx.x >> 6, lane = threadIdx.x & 63;
    int r = blockIdx.x * 4 + wave;
    short8 wv = *(const short8*)(Wfb + (size_t)r * 512 + lane * 8);
    float s = 0.f;
#pragma unroll
    for (int e = 0; e < 8; e++) s += bp[lane * 8 + e] * bfu2f((unsigned short)wv[e]);
#pragma unroll
    for (int o = 32; o > 0; o >>= 1) s += __shfl_down(s, o, 64);
    if (lane == 0) beta[r] = s;
}

// ---------------- logits via MFMA, no X LDS, no k-loop barriers ----------------
// grid (16, 64): x = sg*4 + qh ; y = b. Block: 40 flat (s,n) V-rows, 256 q rows.
// logits[s,b,q,n] = sum_k Xq[b,q,k] * V[(s*64+b)*20+n, k] + beta
__global__ __launch_bounds__(256) void logits_mfma2_k(const float* __restrict__ Xq,
                                                      const unsigned short* __restrict__ Vb,
                                                      const float* __restrict__ beta,
                                                      float* __restrict__ out) {
    __shared__ unsigned short Vs[40 * 512];  // 40 KB, row stride 1024 B, swizzled
    __shared__ float bs[40];
    const int bx = blockIdx.x;
    const int sg = bx >> 2, qh = bx & 3;
    const int b = blockIdx.y;
    const int tid = threadIdx.x, lane = tid & 63, w = tid >> 6;

    // stage V rows [sg*40, sg*40+40) as bf16 (already bf16 in global)
    for (int idx = tid; idx < 40 * 64; idx += 256) {
        int rr = idx >> 6, ch = idx & 63;
        int vr = sg * 40 + rr;
        int s = vr / 20, n = vr - s * 20;
        uint4 u = *(const uint4*)(Vb + (size_t)((s * 64 + b) * 20 + n) * 512 + ch * 8);
        *(uint4*)((char*)Vs + rr * 1024 + ((ch * 16) ^ ((rr & 7) << 4))) = u;
    }
    if (tid < 40) {
        int vr = sg * 40 + tid;
        int s = vr / 20, n = vr - s * 20;
        bs[tid] = beta[(size_t)(s * 64 + b) * 20 + n];
    }
    __syncthreads();

    const int q00 = qh * 256;
    const int klane = (lane >> 4) * 8;
    // per-(q0,qs) bases and X pointers (row = qbase + lane&15, clamped)
    int qbase[2][2];
    const float* xp[2][2];
#pragma unroll
    for (int q0 = 0; q0 < 2; q0++)
#pragma unroll
        for (int qs = 0; qs < 2; qs++) {
            qbase[q0][qs] = q00 + q0 * 128 + w * 32 + qs * 16;
            int qr = qbase[q0][qs] + (lane & 15);
            if (qr > 999) qr = 999;
            xp[q0][qs] = Xq + ((size_t)b * 1000 + qr) * 512 + klane;
        }
    // V-frag row bases (clamped to 39 for discarded lanes)
    int vrow[3], vswz[3];
#pragma unroll
    for (int nf = 0; nf < 3; nf++) {
        int rr = nf * 16 + (lane & 15);
        if (rr > 39) rr = 39;
        vrow[nf] = rr * 1024;
        vswz[nf] = (rr & 7) << 4;
    }

    f32x4 acc[2][2][3] = {};
#pragma unroll 4
    for (int k0 = 0; k0 < 512; k0 += 32) {
        int kb = (k0 + klane) * 2;
        short8 bf[3];
#pragma unroll
        for (int nf = 0; nf < 3; nf++)
            bf[nf] = *(const short8*)((const char*)Vs + vrow[nf] + (kb ^ vswz[nf]));
        short8 af[2][2];
#pragma unroll
        for (int q0 = 0; q0 < 2; q0++)
#pragma unroll
            for (int qs = 0; qs < 2; qs++) {
                const float* p = xp[q0][qs] + k0;
                float4 v0 = *(const float4*)p;
                float4 v1 = *(const float4*)(p + 4);
                uint4 u;
                u.x = cvt2(v0.x, v0.y); u.y = cvt2(v0.z, v0.w);
                u.z = cvt2(v1.x, v1.y); u.w = cvt2(v1.z, v1.w);
                __builtin_memcpy(&af[q0][qs], &u, 16);
            }
#pragma unroll
        for (int q0 = 0; q0 < 2; q0++)
#pragma unroll
            for (int qs = 0; qs < 2; qs++)
#pragma unroll
                for (int nf = 0; nf < 3; nf++)
                    acc[q0][qs][nf] = __builtin_amdgcn_mfma_f32_16x16x32_bf16(af[q0][qs], bf[nf], acc[q0][qs][nf], 0, 0, 0);
    }

    // stores: vr = sg*40 + nf*16 + (lane&15); valid if local row < 40
#pragma unroll
    for (int nf = 0; nf < 3; nf++) {
        int rl = nf * 16 + (lane & 15);
        if (rl < 40) {
            int vr = sg * 40 + rl;
            int s = vr / 20, n = vr - s * 20;
            float bb = bs[rl];
            size_t ob = (size_t)(s * 64 + b) * 20000;
#pragma unroll
            for (int q0 = 0; q0 < 2; q0++)
#pragma unroll
                for (int qs = 0; qs < 2; qs++) {
#pragma unroll
                    for (int j = 0; j < 4; j++) {
                        int q = qbase[q0][qs] + (lane >> 4) * 4 + j;
                        if (q < 1000)
                            out[ob + (size_t)q * 20 + n] = acc[q0][qs][nf][j] + bb;
                    }
                }
        }
    }
}

extern "C" void kernel_launch(void* const* d_in, const int* in_sizes, int n_in,
                              void* d_out, int out_size, void* d_ws, size_t ws_size,
                              hipStream_t stream) {
    const float* x_context = (const float*)d_in[0];
    const int*   y_context = (const int*)d_in[1];
    const float* x_query   = (const float*)d_in[2];
    const float* Wp  = (const float*)d_in[3];
    const float* bp  = (const float*)d_in[4];
    const float* Wa1 = (const float*)d_in[5];
    const float* ba1 = (const float*)d_in[6];
    const float* Wa2 = (const float*)d_in[7];
    const float* ba2 = (const float*)d_in[8];
    const float* Wd1 = (const float*)d_in[9];
    const float* bd1 = (const float*)d_in[10];
    const float* Wd2 = (const float*)d_in[11];
    const float* bd2 = (const float*)d_in[12];

    float* out    = (float*)d_out;
    float* logits = out;                   // 10,240,000 f
    float* z      = out + 10240000;        // 5,242,880 f
    float* mu     = out + 15482880;        // 655,360 f
    float* sc     = out + 16138240;        // 655,360 f
    unsigned short* Wfb = (unsigned short*)d_out;  // bf16 Wf scratch in logits region (consumed before logits written)

    // workspace layout (floats), total ~10.24M floats = 41 MiB
    float* ws   = (float*)d_ws;
    float* A    = ws;                       // 655,360
    float* comb = A + 655360;               // 655,360
    float* h    = comb + 655360;            // 655,360
    float* cnt  = h + 655360;               // 1,280
    float* beta = cnt + 1280;               // 10,240
    unsigned short* WdT1b = (unsigned short*)(beta + 10240);  // 262,144 sh
    unsigned short* WdT2b = WdT1b + 262144;                   // 262,144 sh
    unsigned short* Wpb   = WdT2b + 262144;                   // 262,144 sh
    unsigned short* Vbf   = Wpb + 262144;                     // 5,242,880 sh
    float* big = (float*)(Vbf + 5242880);                     // 5,242,880 f : Apart -> Wg_bf
    unsigned short* Wgb = (unsigned short*)big;               // 5,242,880 sh (after Apart dead)

    // 0) weight prep (independent of data path)
    wtrans_k<<<dim3(8, 8, 2), 256, 0, stream>>>(Wd1, Wd2, WdT1b, WdT2b);
    wconv_k<<<dim3(512), 256, 0, stream>>>(Wp, Wpb, 131072);
    // 1-2) scatter + deterministic reduce -> A (1280,512), cnt
    scatter_k<<<dim3(64, 8), 512, 0, stream>>>(x_context, y_context, big /*Apart*/, beta /*cntpart*/);
    reduce_k<<<dim3(2560), 256, 0, stream>>>(big, beta, A, cnt);
    // 3) combined = relu(A@Wp + cnt*bp)
    gemm_k<1, false><<<dim3(8, 20), 256, 0, stream>>>(A, Wp, bp, cnt, comb, nullptr, 1280, 512, 512);
    // 4) h = gelu(comb@Wa1 + ba1)
    gemm_k<2, false><<<dim3(8, 20), 256, 0, stream>>>(comb, Wa1, ba1, nullptr, h, nullptr, 1280, 512, 512);
    // 5) stats = h@Wa2 + ba2 -> mu, scale
    gemm_k<3, false><<<dim3(16, 20), 256, 0, stream>>>(h, Wa2, ba2, nullptr, mu, sc, 1280, 1024, 512);
    // 6) z = mu + scale*eps
    z_k<<<dim3(20480), 256, 0, stream>>>(mu, sc, z);
    // 7) Wg_bf = gelu(z@Wd1 + bd1)   [MFMA, A fp32 pack]
    gemm_mfma_k<1, 1><<<dim3(4, 160), 256, 0, stream>>>(z, WdT1b, bd1, Wgb);
    // 8) Wf_bf = Wg@Wd2 + bd2        [MFMA, A bf16 direct; out in d_out region]
    gemm_mfma_k<0, 0><<<dim3(4, 160), 256, 0, stream>>>(Wgb, WdT2b, bd2, Wfb);
    // 9) V_bf = Wf @ Wp^T            [MFMA, A bf16 direct]
    gemm_mfma_k<0, 0><<<dim3(4, 160), 256, 0, stream>>>(Wfb, Wpb, nullptr, Vbf);
    // 10) beta[r] = dot(bp, Wf[r,:])
    beta_bf_k<<<dim3(2560), 256, 0, stream>>>(Wfb, bp, beta);
    // 11) logits (overwrites Wf region last)
    logits_mfma2_k<<<dim3(16, 64), 256, 0, stream>>>(x_query, Vbf, beta, logits);
}

// Round 7
// 394.371 us; speedup vs baseline: 2.3990x; 1.1160x over previous
//
#include <hip/hip_runtime.h>
#include <hip/hip_bf16.h>
#include <stdint.h>

// Sizes: BS=64, M=1000, CLIP=512, D=512, N_WAYS=20, N_Z=8
// out = [logits (8,64,1000,20) | z (8,64,20,512) | mu (64,20,512) | scale (64,20,512)]

typedef __attribute__((ext_vector_type(8))) short short8;
typedef __attribute__((ext_vector_type(4))) float f32x4;

__device__ __forceinline__ float gelu_f(float x) {
    return 0.5f * x * (1.0f + erff(x * 0.70710678118654752440f));
}
__device__ __forceinline__ float softplus_f(float x) {
    return fmaxf(x, 0.0f) + log1pf(expf(-fabsf(x)));
}
__device__ __forceinline__ uint32_t cvt2(float a, float b) {  // pack 2 bf16 (RNE)
    __hip_bfloat162 h;
    h.x = __float2bfloat16(a);
    h.y = __float2bfloat16(b);
    uint32_t u; __builtin_memcpy(&u, &h, 4); return u;
}
__device__ __forceinline__ unsigned short f2bfu(float f) {
    __hip_bfloat16 h = __float2bfloat16(f);
    unsigned short u; __builtin_memcpy(&u, &h, 2); return u;
}
__device__ __forceinline__ float bfu2f(unsigned short u) {
    uint32_t v = (uint32_t)u << 16; float f; __builtin_memcpy(&f, &v, 4); return f;
}

// ---------------- threefry2x32 (partitionable) ----------------
__device__ __forceinline__ void threefry2x32(uint32_t k0, uint32_t k1,
                                             uint32_t x0, uint32_t x1,
                                             uint32_t& o0, uint32_t& o1) {
    uint32_t ks[3] = {k0, k1, k0 ^ k1 ^ 0x1BD11BDAu};
    x0 += ks[0]; x1 += ks[1];
    const uint32_t rot[8] = {13,15,26,6,17,29,16,24};
#pragma unroll
    for (int i = 0; i < 5; i++) {
#pragma unroll
        for (int j = 0; j < 4; j++) {
            uint32_t r = rot[(i & 1) * 4 + j];
            x0 += x1;
            x1 = (x1 << r) | (x1 >> (32 - r));
            x1 ^= x0;
        }
        x0 += ks[(i + 1) % 3];
        x1 += ks[(i + 2) % 3] + (uint32_t)(i + 1);
    }
    o0 = x0; o1 = x1;
}

__device__ __forceinline__ float bits_to_normal(uint32_t b) {
    float f = __uint_as_float((b >> 9) | 0x3F800000u) - 1.0f;
    const float lo = __uint_as_float(0xBF7FFFFFu);
    float u = fmaxf(lo, f * 2.0f + lo);
    return 1.41421356237309504880f * erfinvf(u);
}

// ---------------- K1: class scatter partials ----------------
__global__ __launch_bounds__(512) void scatter_k(const float* __restrict__ xc,
                                                 const int* __restrict__ y,
                                                 float* __restrict__ Apart,
                                                 float* __restrict__ cntpart) {
    __shared__ float sA[20 * 512];
    __shared__ float scnt[20];
    const int b = blockIdx.x, ch = blockIdx.y;
    const int tid = threadIdx.x;
    for (int i = tid; i < 20 * 512; i += 512) sA[i] = 0.f;
    if (tid < 20) scnt[tid] = 0.f;
    __syncthreads();
    const int m0 = ch * 125, m1 = m0 + 125;
    for (int m = m0; m < m1; m++) {
        int cls = y[b * 1000 + m];
        sA[cls * 512 + tid] += xc[((size_t)b * 1000 + m) * 512 + tid];
        if (tid == 0) scnt[cls] += 1.f;
    }
    __syncthreads();
    float* dst = Apart + (size_t)ch * 655360 + (size_t)b * 10240;
    for (int i = tid; i < 10240; i += 512) dst[i] = sA[i];
    if (tid < 20) cntpart[(size_t)ch * 1280 + b * 20 + tid] = scnt[tid];
}

// ---------------- K2: fixed-order reduce ----------------
__global__ __launch_bounds__(256) void reduce_k(const float* __restrict__ Apart,
                                                const float* __restrict__ cntpart,
                                                float* __restrict__ A,
                                                float* __restrict__ cnt) {
    int i = blockIdx.x * 256 + threadIdx.x;
    if (i < 655360) {
        float s = 0.f;
#pragma unroll
        for (int p = 0; p < 8; p++) s += Apart[(size_t)p * 655360 + i];
        A[i] = s;
    }
    if (i < 1280) {
        float s = 0.f;
#pragma unroll
        for (int p = 0; p < 8; p++) s += cntpart[p * 1280 + i];
        cnt[i] = s;
    }
}

// ---------------- tiled fp32 GEMM 64x64x16 (small M=1280 chain) ----------------
template <int EPI, bool BT>
__global__ __launch_bounds__(256) void gemm_k(const float* __restrict__ A,
                                              const float* __restrict__ B,
                                              const float* __restrict__ bias,
                                              const float* __restrict__ extra,
                                              float* __restrict__ C0,
                                              float* __restrict__ C1,
                                              int Mm, int Nn, int Kk) {
    __shared__ float As[16][65];
    __shared__ float Bs[16][65];
    const int tid = threadIdx.x;
    const int tx = tid & 15, ty = tid >> 4;
    const int row0 = blockIdx.y * 64, col0 = blockIdx.x * 64;
    float acc[4][4] = {};
    for (int k0 = 0; k0 < Kk; k0 += 16) {
#pragma unroll
        for (int l = 0; l < 4; l++) {
            int idx = tid + l * 256;
            { int mm = idx >> 4, kk = idx & 15;
              As[kk][mm] = A[(size_t)(row0 + mm) * Kk + k0 + kk]; }
            if (BT) { int nn = idx >> 4, kk = idx & 15;
                      Bs[kk][nn] = B[(size_t)(col0 + nn) * Kk + k0 + kk]; }
            else    { int kk = idx >> 6, nn = idx & 63;
                      Bs[kk][nn] = B[(size_t)(k0 + kk) * Nn + col0 + nn]; }
        }
        __syncthreads();
#pragma unroll
        for (int kk = 0; kk < 16; kk++) {
            float a[4], bb[4];
#pragma unroll
            for (int i = 0; i < 4; i++) a[i] = As[kk][ty * 4 + i];
#pragma unroll
            for (int j = 0; j < 4; j++) bb[j] = Bs[kk][tx * 4 + j];
#pragma unroll
            for (int i = 0; i < 4; i++)
#pragma unroll
                for (int j = 0; j < 4; j++) acc[i][j] = fmaf(a[i], bb[j], acc[i][j]);
        }
        __syncthreads();
    }
#pragma unroll
    for (int i = 0; i < 4; i++) {
        int r = row0 + ty * 4 + i;
#pragma unroll
        for (int j = 0; j < 4; j++) {
            int c = col0 + tx * 4 + j;
            float v = acc[i][j];
            if (EPI == 0) {
                if (bias) v += bias[c];
                C0[(size_t)r * Nn + c] = v;
            } else if (EPI == 1) {
                v += extra[r] * bias[c];
                C0[(size_t)r * Nn + c] = fmaxf(v, 0.f);
            } else if (EPI == 2) {
                v += bias[c];
                C0[(size_t)r * Nn + c] = gelu_f(v);
            } else {
                v += bias[c];
                if (c < 512) C0[(size_t)r * 512 + c] = v;
                else C1[(size_t)r * 512 + (c - 512)] = 0.01f + 0.99f * softplus_f(v);
            }
        }
    }
}

// ---------------- z = mu + scale*eps ----------------
__global__ __launch_bounds__(256) void z_k(const float* __restrict__ mu,
                                           const float* __restrict__ sc,
                                           float* __restrict__ z) {
    const uint32_t N = 5242880u;
    uint32_t t = blockIdx.x * 256u + threadIdx.x;
    if (t >= N) return;
    uint32_t o0, o1;
    threefry2x32(0u, 42u, 0u, t, o0, o1);
    uint32_t rem = t % 655360u;
    z[t] = mu[rem] + sc[rem] * bits_to_normal(o0 ^ o1);
}

// ---------------- weight prep: transpose+bf16 (Wd1,Wd2) ----------------
__global__ __launch_bounds__(256) void wtrans_k(const float* __restrict__ W1,
                                                const float* __restrict__ W2,
                                                unsigned short* __restrict__ O1,
                                                unsigned short* __restrict__ O2) {
    __shared__ float T[64][65];
    const float* src = blockIdx.z ? W2 : W1;
    unsigned short* dst = blockIdx.z ? O2 : O1;
    const int r0 = blockIdx.y * 64, c0 = blockIdx.x * 64;
    const int tid = threadIdx.x;
    const int rr = tid >> 4, cc = (tid & 15) * 4;
#pragma unroll
    for (int l = 0; l < 4; l++) {
        int row = rr + l * 16;
        float4 v = *(const float4*)&src[(size_t)(r0 + row) * 512 + c0 + cc];
        T[row][cc] = v.x; T[row][cc+1] = v.y; T[row][cc+2] = v.z; T[row][cc+3] = v.w;
    }
    __syncthreads();
#pragma unroll
    for (int l = 0; l < 4; l++) {
        int n = rr + l * 16;
        uint2 u;
        u.x = cvt2(T[cc][n], T[cc+1][n]);
        u.y = cvt2(T[cc+2][n], T[cc+3][n]);
        *(uint2*)&dst[(size_t)(c0 + n) * 512 + r0 + cc] = u;
    }
}

// ---------------- weight prep: plain bf16 convert (Wp) ----------------
__global__ __launch_bounds__(256) void wconv_k(const float* __restrict__ in,
                                               unsigned short* __restrict__ o, int n2) {
    int i = blockIdx.x * 256 + threadIdx.x;
    if (i < n2) {
        float2 v = *(const float2*)&in[i * 2];
        *(uint32_t*)&o[i * 2] = cvt2(v.x, v.y);
    }
}

// ---------------- bf16 MFMA GEMM: C[M x 512] = act(A @ W + bias), out bf16 ----
template <int APACK, int ACT>
__global__ __launch_bounds__(256) void gemm_mfma_k(const void* __restrict__ Ap,
                                                   const unsigned short* __restrict__ Bbf,
                                                   const float* __restrict__ bias,
                                                   unsigned short* __restrict__ C) {
    __shared__ unsigned short As[64 * 64];    // 8 KB, XOR-swizzled
    __shared__ unsigned short Bs[128 * 64];   // 16 KB
    const int tid = threadIdx.x;
    const int lane = tid & 63, w = tid >> 6;
    const int row0 = blockIdx.y * 64, col0 = blockIdx.x * 128;
    f32x4 acc[4][2] = {};
    for (int k0 = 0; k0 < 512; k0 += 64) {
        {   // stage A (64 rows x 64 k)
            int row = tid >> 2, cs = (tid & 3) * 16;
            int swz = (row & 7) << 4;
            if (APACK) {
                const float* src = (const float*)Ap + (size_t)(row0 + row) * 512 + k0 + cs;
#pragma unroll
                for (int j = 0; j < 2; j++) {
                    float4 v0 = *(const float4*)(src + j * 8);
                    float4 v1 = *(const float4*)(src + j * 8 + 4);
                    uint4 u;
                    u.x = cvt2(v0.x, v0.y); u.y = cvt2(v0.z, v0.w);
                    u.z = cvt2(v1.x, v1.y); u.w = cvt2(v1.z, v1.w);
                    *(uint4*)((char*)As + row * 128 + (((cs + j * 8) * 2) ^ swz)) = u;
                }
            } else {
                const unsigned short* src = (const unsigned short*)Ap + (size_t)(row0 + row) * 512 + k0 + cs;
#pragma unroll
                for (int j = 0; j < 2; j++) {
                    uint4 u = *(const uint4*)(src + j * 8);
                    *(uint4*)((char*)As + row * 128 + (((cs + j * 8) * 2) ^ swz)) = u;
                }
            }
        }
        {   // stage B (128 rows x 64 k), bf16 direct
            int row = tid >> 1, cs = (tid & 1) * 32;
            int swz = (row & 7) << 4;
            const unsigned short* src = Bbf + (size_t)(col0 + row) * 512 + k0 + cs;
#pragma unroll
            for (int j = 0; j < 4; j++) {
                uint4 u = *(const uint4*)(src + j * 8);
                *(uint4*)((char*)Bs + row * 128 + (((cs + j * 8) * 2) ^ swz)) = u;
            }
        }
        __syncthreads();
#pragma unroll
        for (int ks = 0; ks < 2; ks++) {
            short8 a[4], bb[2];
#pragma unroll
            for (int mi = 0; mi < 4; mi++) {
                int r = mi * 16 + (lane & 15);
                a[mi] = *(const short8*)((const char*)As + r * 128 +
                          (((ks * 32 + (lane >> 4) * 8) * 2) ^ ((r & 7) << 4)));
            }
#pragma unroll
            for (int ni = 0; ni < 2; ni++) {
                int n = w * 32 + ni * 16 + (lane & 15);
                bb[ni] = *(const short8*)((const char*)Bs + n * 128 +
                          (((ks * 32 + (lane >> 4) * 8) * 2) ^ ((n & 7) << 4)));
            }
#pragma unroll
            for (int mi = 0; mi < 4; mi++)
#pragma unroll
                for (int ni = 0; ni < 2; ni++)
                    acc[mi][ni] = __builtin_amdgcn_mfma_f32_16x16x32_bf16(a[mi], bb[ni], acc[mi][ni], 0, 0, 0);
        }
        __syncthreads();
    }
#pragma unroll
    for (int mi = 0; mi < 4; mi++) {
#pragma unroll
        for (int ni = 0; ni < 2; ni++) {
            int c = col0 + w * 32 + ni * 16 + (lane & 15);
            float bv = bias ? bias[c] : 0.f;
#pragma unroll
            for (int j = 0; j < 4; j++) {
                int r = row0 + mi * 16 + (lane >> 4) * 4 + j;
                float v = acc[mi][ni][j] + bv;
                if (ACT) v = gelu_f(v);
                C[(size_t)r * 512 + c] = f2bfu(v);
            }
        }
    }
}

// ---------------- beta[r] = dot(bp, Wf_bf[r,:]) ----------------
__global__ __launch_bounds__(256) void beta_bf_k(const unsigned short* __restrict__ Wfb,
                                                 const float* __restrict__ bp,
                                                 float* __restrict__ beta) {
    int wave = threadIdx.x >> 6, lane = threadIdx.x & 63;
    int r = blockIdx.x * 4 + wave;
    short8 wv = *(const short8*)(Wfb + (size_t)r * 512 + lane * 8);
    float s = 0.f;
#pragma unroll
    for (int e = 0; e < 8; e++) s += bp[lane * 8 + e] * bfu2f((unsigned short)wv[e]);
#pragma unroll
    for (int o = 32; o > 0; o >>= 1) s += __shfl_down(s, o, 64);
    if (lane == 0) beta[r] = s;
}

// ---------------- logits v3: one block = 128 q x ALL 160 (s,n) rows ----------
// X read exactly once; V streamed per-64k-slice into 20KB LDS; XCD-aware remap
// so the 8 qh-blocks of one b share an XCD L2 for V.
__global__ __launch_bounds__(512) void logits_mfma3_k(const float* __restrict__ Xq,
                                                      const unsigned short* __restrict__ Vb,
                                                      const float* __restrict__ beta,
                                                      float* __restrict__ out) {
    __shared__ unsigned short Vs[160 * 64];  // 20 KB, row stride 128 B, swizzled
    __shared__ float bs[160];
    // XCD remap: linear u -> (b, qh) with b%8 == u%8 (same-b blocks on same XCD)
    const int u = blockIdx.x + 8 * blockIdx.y;       // grid (8,64) -> u in [0,512)
    const int xcd = u & 7, idx = u >> 3;             // idx in [0,64)
    const int b = (idx & 7) * 8 + xcd;
    const int qh = idx >> 3;                         // [0,8)
    const int tid = threadIdx.x, lane = tid & 63, w = tid >> 6;
    const int wq = w >> 1, wn = w & 1;

    // beta -> LDS
    if (tid < 160) {
        int s = tid / 20, n = tid - s * 20;
        bs[tid] = beta[(size_t)(s * 64 + b) * 20 + n];
    }

    const int klane = (lane >> 4) * 8;
    // X pointers: q row per (qs), clamped
    const float* xp[2];
    int qb[2];
#pragma unroll
    for (int qs = 0; qs < 2; qs++) {
        qb[qs] = qh * 128 + wq * 32 + qs * 16;
        int qr = qb[qs] + (lane & 15);
        if (qr > 999) qr = 999;
        xp[qs] = Xq + ((size_t)b * 1000 + qr) * 512 + klane;
    }
    // V-frag rows for this wave (all valid: 160 = 10*16)
    int vrow[5], vswz[5];
#pragma unroll
    for (int nf = 0; nf < 5; nf++) {
        int rr = wn * 80 + nf * 16 + (lane & 15);
        vrow[nf] = rr * 128;
        vswz[nf] = (rr & 7) << 4;
    }

    f32x4 acc[2][5] = {};
    for (int k0 = 0; k0 < 512; k0 += 64) {
        __syncthreads();
        // stage V k-slice: 160 rows x 64 k bf16 = 20 KB; chunk = 32 B
        for (int c = tid; c < 640; c += 512) {
            int row = c >> 2, off = (c & 3) * 32;        // byte offset in 128B row
            int sdiv = row / 20;
            int row_g = row + sdiv * 1260 + b * 20;      // (s*64+b)*20+n
            const unsigned short* src = Vb + (size_t)row_g * 512 + k0 + (c & 3) * 16;
            uint4 u0 = *(const uint4*)src;
            uint4 u1 = *(const uint4*)(src + 8);
            int swz = (row & 7) << 4;
            char* base = (char*)Vs + row * 128;
            *(uint4*)(base + (off ^ swz)) = u0;
            *(uint4*)(base + ((off + 16) ^ swz)) = u1;
        }
        __syncthreads();
#pragma unroll
        for (int ks = 0; ks < 2; ks++) {
            int kb = (ks * 32 + klane) * 2;
            short8 bf[5];
#pragma unroll
            for (int nf = 0; nf < 5; nf++)
                bf[nf] = *(const short8*)((const char*)Vs + vrow[nf] + (kb ^ vswz[nf]));
            short8 af[2];
#pragma unroll
            for (int qs = 0; qs < 2; qs++) {
                const float* p = xp[qs] + k0 + ks * 32;
                float4 v0 = *(const float4*)p;
                float4 v1 = *(const float4*)(p + 4);
                uint4 uu;
                uu.x = cvt2(v0.x, v0.y); uu.y = cvt2(v0.z, v0.w);
                uu.z = cvt2(v1.x, v1.y); uu.w = cvt2(v1.z, v1.w);
                __builtin_memcpy(&af[qs], &uu, 16);
            }
#pragma unroll
            for (int qs = 0; qs < 2; qs++)
#pragma unroll
                for (int nf = 0; nf < 5; nf++)
                    acc[qs][nf] = __builtin_amdgcn_mfma_f32_16x16x32_bf16(af[qs], bf[nf], acc[qs][nf], 0, 0, 0);
        }
    }

    // store
#pragma unroll
    for (int nf = 0; nf < 5; nf++) {
        int rl = wn * 80 + nf * 16 + (lane & 15);
        int s = rl / 20, n = rl - s * 20;
        float bb = bs[rl];
        size_t ob = (size_t)(s * 64 + b) * 20000;
#pragma unroll
        for (int qs = 0; qs < 2; qs++) {
#pragma unroll
            for (int j = 0; j < 4; j++) {
                int q = qb[qs] + (lane >> 4) * 4 + j;
                if (q < 1000)
                    out[ob + (size_t)q * 20 + n] = acc[qs][nf][j] + bb;
            }
        }
    }
}

extern "C" void kernel_launch(void* const* d_in, const int* in_sizes, int n_in,
                              void* d_out, int out_size, void* d_ws, size_t ws_size,
                              hipStream_t stream) {
    const float* x_context = (const float*)d_in[0];
    const int*   y_context = (const int*)d_in[1];
    const float* x_query   = (const float*)d_in[2];
    const float* Wp  = (const float*)d_in[3];
    const float* bp  = (const float*)d_in[4];
    const float* Wa1 = (const float*)d_in[5];
    const float* ba1 = (const float*)d_in[6];
    const float* Wa2 = (const float*)d_in[7];
    const float* ba2 = (const float*)d_in[8];
    const float* Wd1 = (const float*)d_in[9];
    const float* bd1 = (const float*)d_in[10];
    const float* Wd2 = (const float*)d_in[11];
    const float* bd2 = (const float*)d_in[12];

    float* out    = (float*)d_out;
    float* logits = out;                   // 10,240,000 f
    float* z      = out + 10240000;        // 5,242,880 f
    float* mu     = out + 15482880;        // 655,360 f
    float* sc     = out + 16138240;        // 655,360 f
    unsigned short* Wfb = (unsigned short*)d_out;  // bf16 Wf scratch in logits region

    // workspace layout
    float* ws   = (float*)d_ws;
    float* A    = ws;                       // 655,360
    float* comb = A + 655360;               // 655,360
    float* h    = comb + 655360;            // 655,360
    float* cnt  = h + 655360;               // 1,280
    float* beta = cnt + 1280;               // 10,240
    unsigned short* WdT1b = (unsigned short*)(beta + 10240);  // 262,144 sh
    unsigned short* WdT2b = WdT1b + 262144;                   // 262,144 sh
    unsigned short* Wpb   = WdT2b + 262144;                   // 262,144 sh
    unsigned short* Vbf   = Wpb + 262144;                     // 5,242,880 sh
    float* big = (float*)(Vbf + 5242880);                     // 5,242,880 f : Apart -> Wg_bf
    unsigned short* Wgb = (unsigned short*)big;

    // 0) weight prep
    wtrans_k<<<dim3(8, 8, 2), 256, 0, stream>>>(Wd1, Wd2, WdT1b, WdT2b);
    wconv_k<<<dim3(512), 256, 0, stream>>>(Wp, Wpb, 131072);
    // 1-2) scatter + deterministic reduce -> A (1280,512), cnt
    scatter_k<<<dim3(64, 8), 512, 0, stream>>>(x_context, y_context, big /*Apart*/, beta /*cntpart*/);
    reduce_k<<<dim3(2560), 256, 0, stream>>>(big, beta, A, cnt);
    // 3) combined = relu(A@Wp + cnt*bp)
    gemm_k<1, false><<<dim3(8, 20), 256, 0, stream>>>(A, Wp, bp, cnt, comb, nullptr, 1280, 512, 512);
    // 4) h = gelu(comb@Wa1 + ba1)
    gemm_k<2, false><<<dim3(8, 20), 256, 0, stream>>>(comb, Wa1, ba1, nullptr, h, nullptr, 1280, 512, 512);
    // 5) stats = h@Wa2 + ba2 -> mu, scale
    gemm_k<3, false><<<dim3(16, 20), 256, 0, stream>>>(h, Wa2, ba2, nullptr, mu, sc, 1280, 1024, 512);
    // 6) z = mu + scale*eps
    z_k<<<dim3(20480), 256, 0, stream>>>(mu, sc, z);
    // 7) Wg_bf = gelu(z@Wd1 + bd1)   [MFMA, A fp32 pack]
    gemm_mfma_k<1, 1><<<dim3(4, 160), 256, 0, stream>>>(z, WdT1b, bd1, Wgb);
    // 8) Wf_bf = Wg@Wd2 + bd2        [MFMA]
    gemm_mfma_k<0, 0><<<dim3(4, 160), 256, 0, stream>>>(Wgb, WdT2b, bd2, Wfb);
    // 9) V_bf = Wf @ Wp^T            [MFMA]
    gemm_mfma_k<0, 0><<<dim3(4, 160), 256, 0, stream>>>(Wfb, Wpb, nullptr, Vbf);
    // 10) beta[r] = dot(bp, Wf[r,:])
    beta_bf_k<<<dim3(2560), 256, 0, stream>>>(Wfb, bp, beta);
    // 11) logits (overwrites Wf region last)
    logits_mfma3_k<<<dim3(8, 64), 512, 0, stream>>>(x_query, Vbf, beta, logits);
}

// Round 8
// 355.404 us; speedup vs baseline: 2.6620x; 1.1096x over previous
//
#include <hip/hip_runtime.h>
#include <hip/hip_bf16.h>
#include <stdint.h>

// Sizes: BS=64, M=1000, CLIP=512, D=512, N_WAYS=20, N_Z=8
// out = [logits (8,64,1000,20) | z (8,64,20,512) | mu (64,20,512) | scale (64,20,512)]

typedef __attribute__((ext_vector_type(8))) short short8;
typedef __attribute__((ext_vector_type(4))) float f32x4;

__device__ __forceinline__ float gelu_f(float x) {
    return 0.5f * x * (1.0f + erff(x * 0.70710678118654752440f));
}
__device__ __forceinline__ float softplus_f(float x) {
    return fmaxf(x, 0.0f) + log1pf(expf(-fabsf(x)));
}
__device__ __forceinline__ uint32_t cvt2(float a, float b) {  // pack 2 bf16 (RNE)
    __hip_bfloat162 h;
    h.x = __float2bfloat16(a);
    h.y = __float2bfloat16(b);
    uint32_t u; __builtin_memcpy(&u, &h, 4); return u;
}
__device__ __forceinline__ unsigned short f2bfu(float f) {
    __hip_bfloat16 h = __float2bfloat16(f);
    unsigned short u; __builtin_memcpy(&u, &h, 2); return u;
}
__device__ __forceinline__ float bfu2f(unsigned short u) {
    uint32_t v = (uint32_t)u << 16; float f; __builtin_memcpy(&f, &v, 4); return f;
}

// ---------------- threefry2x32 (partitionable) ----------------
__device__ __forceinline__ void threefry2x32(uint32_t k0, uint32_t k1,
                                             uint32_t x0, uint32_t x1,
                                             uint32_t& o0, uint32_t& o1) {
    uint32_t ks[3] = {k0, k1, k0 ^ k1 ^ 0x1BD11BDAu};
    x0 += ks[0]; x1 += ks[1];
    const uint32_t rot[8] = {13,15,26,6,17,29,16,24};
#pragma unroll
    for (int i = 0; i < 5; i++) {
#pragma unroll
        for (int j = 0; j < 4; j++) {
            uint32_t r = rot[(i & 1) * 4 + j];
            x0 += x1;
            x1 = (x1 << r) | (x1 >> (32 - r));
            x1 ^= x0;
        }
        x0 += ks[(i + 1) % 3];
        x1 += ks[(i + 2) % 3] + (uint32_t)(i + 1);
    }
    o0 = x0; o1 = x1;
}

__device__ __forceinline__ float bits_to_normal(uint32_t b) {
    float f = __uint_as_float((b >> 9) | 0x3F800000u) - 1.0f;
    const float lo = __uint_as_float(0xBF7FFFFFu);
    float u = fmaxf(lo, f * 2.0f + lo);
    return 1.41421356237309504880f * erfinvf(u);
}

// ---------------- K1: class scatter partials, software-pipelined ----------------
// per (b, ch): 125 m's; register panels of 8 (x, cls) prefetched while the
// previous panel accumulates into LDS -> 8 loads in flight cover HBM latency.
__global__ __launch_bounds__(512) void scatter_k(const float* __restrict__ xc,
                                                 const int* __restrict__ y,
                                                 float* __restrict__ Apart,
                                                 float* __restrict__ cntpart) {
    __shared__ float sA[20 * 512];
    __shared__ float scnt[20];
    const int b = blockIdx.x, ch = blockIdx.y;
    const int tid = threadIdx.x;
    for (int i = tid; i < 20 * 512; i += 512) sA[i] = 0.f;
    if (tid < 20) scnt[tid] = 0.f;
    __syncthreads();
    const int m0 = ch * 125;
    const size_t xbase = ((size_t)b * 1000 + m0) * 512 + tid;
    const int ybase = b * 1000 + m0;

    float xv[8]; int cv[8];
#pragma unroll
    for (int j = 0; j < 8; j++) {
        xv[j] = xc[xbase + (size_t)j * 512];
        cv[j] = y[ybase + j];
    }
    int p = 8;
    for (int pan = 0; pan < 15; pan++) {
        float xn[8]; int cn[8];
        const bool more = (pan < 14);
        if (more) {
#pragma unroll
            for (int j = 0; j < 8; j++) {
                xn[j] = xc[xbase + (size_t)(p + j) * 512];
                cn[j] = y[ybase + p + j];
            }
        }
#pragma unroll
        for (int j = 0; j < 8; j++) {
            sA[cv[j] * 512 + tid] += xv[j];
            if (tid == 0) scnt[cv[j]] += 1.f;
        }
        if (more) {
#pragma unroll
            for (int j = 0; j < 8; j++) { xv[j] = xn[j]; cv[j] = cn[j]; }
            p += 8;
        }
    }
    // tail: m = m0+120 .. m0+124
#pragma unroll
    for (int j = 0; j < 5; j++) {
        float xx = xc[xbase + (size_t)(120 + j) * 512];
        int cc = y[ybase + 120 + j];
        sA[cc * 512 + tid] += xx;
        if (tid == 0) scnt[cc] += 1.f;
    }
    __syncthreads();
    float* dst = Apart + (size_t)ch * 655360 + (size_t)b * 10240;
    for (int i = tid; i < 10240; i += 512) dst[i] = sA[i];
    if (tid < 20) cntpart[(size_t)ch * 1280 + b * 20 + tid] = scnt[tid];
}

// ---------------- K2: fixed-order reduce (float4) ----------------
__global__ __launch_bounds__(256) void reduce_k(const float* __restrict__ Apart,
                                                const float* __restrict__ cntpart,
                                                float* __restrict__ A,
                                                float* __restrict__ cnt) {
    int i = blockIdx.x * 256 + threadIdx.x;
    if (i < 163840) {
        const float4* Ap4 = (const float4*)Apart;
        float4 s = Ap4[i];
#pragma unroll
        for (int p = 1; p < 8; p++) {
            float4 v = Ap4[(size_t)p * 163840 + i];
            s.x += v.x; s.y += v.y; s.z += v.z; s.w += v.w;
        }
        ((float4*)A)[i] = s;
    }
    if (i < 1280) {
        float s = 0.f;
#pragma unroll
        for (int p = 0; p < 8; p++) s += cntpart[p * 1280 + i];
        cnt[i] = s;
    }
}

// ---------------- tiled fp32 GEMM 64x64x16 (small M=1280 chain) ----------------
template <int EPI, bool BT>
__global__ __launch_bounds__(256) void gemm_k(const float* __restrict__ A,
                                              const float* __restrict__ B,
                                              const float* __restrict__ bias,
                                              const float* __restrict__ extra,
                                              float* __restrict__ C0,
                                              float* __restrict__ C1,
                                              int Mm, int Nn, int Kk) {
    __shared__ float As[16][65];
    __shared__ float Bs[16][65];
    const int tid = threadIdx.x;
    const int tx = tid & 15, ty = tid >> 4;
    const int row0 = blockIdx.y * 64, col0 = blockIdx.x * 64;
    float acc[4][4] = {};
    for (int k0 = 0; k0 < Kk; k0 += 16) {
#pragma unroll
        for (int l = 0; l < 4; l++) {
            int idx = tid + l * 256;
            { int mm = idx >> 4, kk = idx & 15;
              As[kk][mm] = A[(size_t)(row0 + mm) * Kk + k0 + kk]; }
            if (BT) { int nn = idx >> 4, kk = idx & 15;
                      Bs[kk][nn] = B[(size_t)(col0 + nn) * Kk + k0 + kk]; }
            else    { int kk = idx >> 6, nn = idx & 63;
                      Bs[kk][nn] = B[(size_t)(k0 + kk) * Nn + col0 + nn]; }
        }
        __syncthreads();
#pragma unroll
        for (int kk = 0; kk < 16; kk++) {
            float a[4], bb[4];
#pragma unroll
            for (int i = 0; i < 4; i++) a[i] = As[kk][ty * 4 + i];
#pragma unroll
            for (int j = 0; j < 4; j++) bb[j] = Bs[kk][tx * 4 + j];
#pragma unroll
            for (int i = 0; i < 4; i++)
#pragma unroll
                for (int j = 0; j < 4; j++) acc[i][j] = fmaf(a[i], bb[j], acc[i][j]);
        }
        __syncthreads();
    }
#pragma unroll
    for (int i = 0; i < 4; i++) {
        int r = row0 + ty * 4 + i;
#pragma unroll
        for (int j = 0; j < 4; j++) {
            int c = col0 + tx * 4 + j;
            float v = acc[i][j];
            if (EPI == 0) {
                if (bias) v += bias[c];
                C0[(size_t)r * Nn + c] = v;
            } else if (EPI == 1) {
                v += extra[r] * bias[c];
                C0[(size_t)r * Nn + c] = fmaxf(v, 0.f);
            } else if (EPI == 2) {
                v += bias[c];
                C0[(size_t)r * Nn + c] = gelu_f(v);
            } else {
                v += bias[c];
                if (c < 512) C0[(size_t)r * 512 + c] = v;
                else C1[(size_t)r * 512 + (c - 512)] = 0.01f + 0.99f * softplus_f(v);
            }
        }
    }
}

// ---------------- z = mu + scale*eps ----------------
__global__ __launch_bounds__(256) void z_k(const float* __restrict__ mu,
                                           const float* __restrict__ sc,
                                           float* __restrict__ z) {
    const uint32_t N = 5242880u;
    uint32_t t = blockIdx.x * 256u + threadIdx.x;
    if (t >= N) return;
    uint32_t o0, o1;
    threefry2x32(0u, 42u, 0u, t, o0, o1);
    uint32_t rem = t % 655360u;
    z[t] = mu[rem] + sc[rem] * bits_to_normal(o0 ^ o1);
}

// ---------------- weight prep: transpose+bf16 (Wd1,Wd2) ----------------
__global__ __launch_bounds__(256) void wtrans_k(const float* __restrict__ W1,
                                                const float* __restrict__ W2,
                                                unsigned short* __restrict__ O1,
                                                unsigned short* __restrict__ O2) {
    __shared__ float T[64][65];
    const float* src = blockIdx.z ? W2 : W1;
    unsigned short* dst = blockIdx.z ? O2 : O1;
    const int r0 = blockIdx.y * 64, c0 = blockIdx.x * 64;
    const int tid = threadIdx.x;
    const int rr = tid >> 4, cc = (tid & 15) * 4;
#pragma unroll
    for (int l = 0; l < 4; l++) {
        int row = rr + l * 16;
        float4 v = *(const float4*)&src[(size_t)(r0 + row) * 512 + c0 + cc];
        T[row][cc] = v.x; T[row][cc+1] = v.y; T[row][cc+2] = v.z; T[row][cc+3] = v.w;
    }
    __syncthreads();
#pragma unroll
    for (int l = 0; l < 4; l++) {
        int n = rr + l * 16;
        uint2 u;
        u.x = cvt2(T[cc][n], T[cc+1][n]);
        u.y = cvt2(T[cc+2][n], T[cc+3][n]);
        *(uint2*)&dst[(size_t)(c0 + n) * 512 + r0 + cc] = u;
    }
}

// ---------------- weight prep: plain bf16 convert (Wp) ----------------
__global__ __launch_bounds__(256) void wconv_k(const float* __restrict__ in,
                                               unsigned short* __restrict__ o, int n2) {
    int i = blockIdx.x * 256 + threadIdx.x;
    if (i < n2) {
        float2 v = *(const float2*)&in[i * 2];
        *(uint32_t*)&o[i * 2] = cvt2(v.x, v.y);
    }
}

// ---------------- bf16 MFMA GEMM: C[M x 512] = act(A @ W + bias), out bf16 ----
template <int APACK, int ACT>
__global__ __launch_bounds__(256) void gemm_mfma_k(const void* __restrict__ Ap,
                                                   const unsigned short* __restrict__ Bbf,
                                                   const float* __restrict__ bias,
                                                   unsigned short* __restrict__ C) {
    __shared__ unsigned short As[64 * 64];    // 8 KB, XOR-swizzled
    __shared__ unsigned short Bs[128 * 64];   // 16 KB
    const int tid = threadIdx.x;
    const int lane = tid & 63, w = tid >> 6;
    const int row0 = blockIdx.y * 64, col0 = blockIdx.x * 128;
    f32x4 acc[4][2] = {};
    for (int k0 = 0; k0 < 512; k0 += 64) {
        {   // stage A (64 rows x 64 k)
            int row = tid >> 2, cs = (tid & 3) * 16;
            int swz = (row & 7) << 4;
            if (APACK) {
                const float* src = (const float*)Ap + (size_t)(row0 + row) * 512 + k0 + cs;
#pragma unroll
                for (int j = 0; j < 2; j++) {
                    float4 v0 = *(const float4*)(src + j * 8);
                    float4 v1 = *(const float4*)(src + j * 8 + 4);
                    uint4 u;
                    u.x = cvt2(v0.x, v0.y); u.y = cvt2(v0.z, v0.w);
                    u.z = cvt2(v1.x, v1.y); u.w = cvt2(v1.z, v1.w);
                    *(uint4*)((char*)As + row * 128 + (((cs + j * 8) * 2) ^ swz)) = u;
                }
            } else {
                const unsigned short* src = (const unsigned short*)Ap + (size_t)(row0 + row) * 512 + k0 + cs;
#pragma unroll
                for (int j = 0; j < 2; j++) {
                    uint4 u = *(const uint4*)(src + j * 8);
                    *(uint4*)((char*)As + row * 128 + (((cs + j * 8) * 2) ^ swz)) = u;
                }
            }
        }
        {   // stage B (128 rows x 64 k), bf16 direct
            int row = tid >> 1, cs = (tid & 1) * 32;
            int swz = (row & 7) << 4;
            const unsigned short* src = Bbf + (size_t)(col0 + row) * 512 + k0 + cs;
#pragma unroll
            for (int j = 0; j < 4; j++) {
                uint4 u = *(const uint4*)(src + j * 8);
                *(uint4*)((char*)Bs + row * 128 + (((cs + j * 8) * 2) ^ swz)) = u;
            }
        }
        __syncthreads();
#pragma unroll
        for (int ks = 0; ks < 2; ks++) {
            short8 a[4], bb[2];
#pragma unroll
            for (int mi = 0; mi < 4; mi++) {
                int r = mi * 16 + (lane & 15);
                a[mi] = *(const short8*)((const char*)As + r * 128 +
                          (((ks * 32 + (lane >> 4) * 8) * 2) ^ ((r & 7) << 4)));
            }
#pragma unroll
            for (int ni = 0; ni < 2; ni++) {
                int n = w * 32 + ni * 16 + (lane & 15);
                bb[ni] = *(const short8*)((const char*)Bs + n * 128 +
                          (((ks * 32 + (lane >> 4) * 8) * 2) ^ ((n & 7) << 4)));
            }
#pragma unroll
            for (int mi = 0; mi < 4; mi++)
#pragma unroll
                for (int ni = 0; ni < 2; ni++)
                    acc[mi][ni] = __builtin_amdgcn_mfma_f32_16x16x32_bf16(a[mi], bb[ni], acc[mi][ni], 0, 0, 0);
        }
        __syncthreads();
    }
#pragma unroll
    for (int mi = 0; mi < 4; mi++) {
#pragma unroll
        for (int ni = 0; ni < 2; ni++) {
            int c = col0 + w * 32 + ni * 16 + (lane & 15);
            float bv = bias ? bias[c] : 0.f;
#pragma unroll
            for (int j = 0; j < 4; j++) {
                int r = row0 + mi * 16 + (lane >> 4) * 4 + j;
                float v = acc[mi][ni][j] + bv;
                if (ACT) v = gelu_f(v);
                C[(size_t)r * 512 + c] = f2bfu(v);
            }
        }
    }
}

// ---------------- beta[r] = dot(bp, Wf_bf[r,:]) ----------------
__global__ __launch_bounds__(256) void beta_bf_k(const unsigned short* __restrict__ Wfb,
                                                 const float* __restrict__ bp,
                                                 float* __restrict__ beta) {
    int wave = threadIdx.x >> 6, lane = threadIdx.x & 63;
    int r = blockIdx.x * 4 + wave;
    short8 wv = *(const short8*)(Wfb + (size_t)r * 512 + lane * 8);
    float s = 0.f;
#pragma unroll
    for (int e = 0; e < 8; e++) s += bp[lane * 8 + e] * bfu2f((unsigned short)wv[e]);
#pragma unroll
    for (int o = 32; o > 0; o >>= 1) s += __shfl_down(s, o, 64);
    if (lane == 0) beta[r] = s;
}

// ---------------- logits v3: one block = 128 q x ALL 160 (s,n) rows ----------
__global__ __launch_bounds__(512) void logits_mfma3_k(const float* __restrict__ Xq,
                                                      const unsigned short* __restrict__ Vb,
                                                      const float* __restrict__ beta,
                                                      float* __restrict__ out) {
    __shared__ unsigned short Vs[160 * 64];  // 20 KB, row stride 128 B, swizzled
    __shared__ float bs[160];
    const int u = blockIdx.x + 8 * blockIdx.y;       // grid (8,64) -> u in [0,512)
    const int xcd = u & 7, idx = u >> 3;
    const int b = (idx & 7) * 8 + xcd;
    const int qh = idx >> 3;
    const int tid = threadIdx.x, lane = tid & 63, w = tid >> 6;
    const int wq = w >> 1, wn = w & 1;

    if (tid < 160) {
        int s = tid / 20, n = tid - s * 20;
        bs[tid] = beta[(size_t)(s * 64 + b) * 20 + n];
    }

    const int klane = (lane >> 4) * 8;
    const float* xp[2];
    int qb[2];
#pragma unroll
    for (int qs = 0; qs < 2; qs++) {
        qb[qs] = qh * 128 + wq * 32 + qs * 16;
        int qr = qb[qs] + (lane & 15);
        if (qr > 999) qr = 999;
        xp[qs] = Xq + ((size_t)b * 1000 + qr) * 512 + klane;
    }
    int vrow[5], vswz[5];
#pragma unroll
    for (int nf = 0; nf < 5; nf++) {
        int rr = wn * 80 + nf * 16 + (lane & 15);
        vrow[nf] = rr * 128;
        vswz[nf] = (rr & 7) << 4;
    }

    f32x4 acc[2][5] = {};
    for (int k0 = 0; k0 < 512; k0 += 64) {
        __syncthreads();
        for (int c = tid; c < 640; c += 512) {
            int row = c >> 2, off = (c & 3) * 32;
            int sdiv = row / 20;
            int row_g = row + sdiv * 1260 + b * 20;
            const unsigned short* src = Vb + (size_t)row_g * 512 + k0 + (c & 3) * 16;
            uint4 u0 = *(const uint4*)src;
            uint4 u1 = *(const uint4*)(src + 8);
            int swz = (row & 7) << 4;
            char* base = (char*)Vs + row * 128;
            *(uint4*)(base + (off ^ swz)) = u0;
            *(uint4*)(base + ((off + 16) ^ swz)) = u1;
        }
        __syncthreads();
#pragma unroll
        for (int ks = 0; ks < 2; ks++) {
            int kb = (ks * 32 + klane) * 2;
            short8 bf[5];
#pragma unroll
            for (int nf = 0; nf < 5; nf++)
                bf[nf] = *(const short8*)((const char*)Vs + vrow[nf] + (kb ^ vswz[nf]));
            short8 af[2];
#pragma unroll
            for (int qs = 0; qs < 2; qs++) {
                const float* p = xp[qs] + k0 + ks * 32;
                float4 v0 = *(const float4*)p;
                float4 v1 = *(const float4*)(p + 4);
                uint4 uu;
                uu.x = cvt2(v0.x, v0.y); uu.y = cvt2(v0.z, v0.w);
                uu.z = cvt2(v1.x, v1.y); uu.w = cvt2(v1.z, v1.w);
                __builtin_memcpy(&af[qs], &uu, 16);
            }
#pragma unroll
            for (int qs = 0; qs < 2; qs++)
#pragma unroll
                for (int nf = 0; nf < 5; nf++)
                    acc[qs][nf] = __builtin_amdgcn_mfma_f32_16x16x32_bf16(af[qs], bf[nf], acc[qs][nf], 0, 0, 0);
        }
    }

#pragma unroll
    for (int nf = 0; nf < 5; nf++) {
        int rl = wn * 80 + nf * 16 + (lane & 15);
        int s = rl / 20, n = rl - s * 20;
        float bb = bs[rl];
        size_t ob = (size_t)(s * 64 + b) * 20000;
#pragma unroll
        for (int qs = 0; qs < 2; qs++) {
#pragma unroll
            for (int j = 0; j < 4; j++) {
                int q = qb[qs] + (lane >> 4) * 4 + j;
                if (q < 1000)
                    out[ob + (size_t)q * 20 + n] = acc[qs][nf][j] + bb;
            }
        }
    }
}

extern "C" void kernel_launch(void* const* d_in, const int* in_sizes, int n_in,
                              void* d_out, int out_size, void* d_ws, size_t ws_size,
                              hipStream_t stream) {
    const float* x_context = (const float*)d_in[0];
    const int*   y_context = (const int*)d_in[1];
    const float* x_query   = (const float*)d_in[2];
    const float* Wp  = (const float*)d_in[3];
    const float* bp  = (const float*)d_in[4];
    const float* Wa1 = (const float*)d_in[5];
    const float* ba1 = (const float*)d_in[6];
    const float* Wa2 = (const float*)d_in[7];
    const float* ba2 = (const float*)d_in[8];
    const float* Wd1 = (const float*)d_in[9];
    const float* bd1 = (const float*)d_in[10];
    const float* Wd2 = (const float*)d_in[11];
    const float* bd2 = (const float*)d_in[12];

    float* out    = (float*)d_out;
    float* logits = out;                   // 10,240,000 f
    float* z      = out + 10240000;        // 5,242,880 f
    float* mu     = out + 15482880;        // 655,360 f
    float* sc     = out + 16138240;        // 655,360 f
    unsigned short* Wfb = (unsigned short*)d_out;  // bf16 Wf scratch in logits region

    // workspace layout
    float* ws   = (float*)d_ws;
    float* A    = ws;                       // 655,360
    float* comb = A + 655360;               // 655,360
    float* h    = comb + 655360;            // 655,360
    float* cnt  = h + 655360;               // 1,280
    float* beta = cnt + 1280;               // 10,240
    unsigned short* WdT1b = (unsigned short*)(beta + 10240);  // 262,144 sh
    unsigned short* WdT2b = WdT1b + 262144;                   // 262,144 sh
    unsigned short* Wpb   = WdT2b + 262144;                   // 262,144 sh
    unsigned short* Vbf   = Wpb + 262144;                     // 5,242,880 sh
    float* big = (float*)(Vbf + 5242880);                     // 5,242,880 f : Apart -> Wg_bf
    unsigned short* Wgb = (unsigned short*)big;

    // 0) weight prep
    wtrans_k<<<dim3(8, 8, 2), 256, 0, stream>>>(Wd1, Wd2, WdT1b, WdT2b);
    wconv_k<<<dim3(512), 256, 0, stream>>>(Wp, Wpb, 131072);
    // 1-2) scatter + deterministic reduce -> A (1280,512), cnt
    scatter_k<<<dim3(64, 8), 512, 0, stream>>>(x_context, y_context, big /*Apart*/, beta /*cntpart*/);
    reduce_k<<<dim3(640), 256, 0, stream>>>(big, beta, A, cnt);
    // 3) combined = relu(A@Wp + cnt*bp)
    gemm_k<1, false><<<dim3(8, 20), 256, 0, stream>>>(A, Wp, bp, cnt, comb, nullptr, 1280, 512, 512);
    // 4) h = gelu(comb@Wa1 + ba1)
    gemm_k<2, false><<<dim3(8, 20), 256, 0, stream>>>(comb, Wa1, ba1, nullptr, h, nullptr, 1280, 512, 512);
    // 5) stats = h@Wa2 + ba2 -> mu, scale
    gemm_k<3, false><<<dim3(16, 20), 256, 0, stream>>>(h, Wa2, ba2, nullptr, mu, sc, 1280, 1024, 512);
    // 6) z = mu + scale*eps
    z_k<<<dim3(20480), 256, 0, stream>>>(mu, sc, z);
    // 7) Wg_bf = gelu(z@Wd1 + bd1)   [MFMA, A fp32 pack]
    gemm_mfma_k<1, 1><<<dim3(4, 160), 256, 0, stream>>>(z, WdT1b, bd1, Wgb);
    // 8) Wf_bf = Wg@Wd2 + bd2        [MFMA]
    gemm_mfma_k<0, 0><<<dim3(4, 160), 256, 0, stream>>>(Wgb, WdT2b, bd2, Wfb);
    // 9) V_bf = Wf @ Wp^T            [MFMA]
    gemm_mfma_k<0, 0><<<dim3(4, 160), 256, 0, stream>>>(Wfb, Wpb, nullptr, Vbf);
    // 10) beta[r] = dot(bp, Wf[r,:])
    beta_bf_k<<<dim3(2560), 256, 0, stream>>>(Wfb, bp, beta);
    // 11) logits (overwrites Wf region last)
    logits_mfma3_k<<<dim3(8, 64), 512, 0, stream>>>(x_query, Vbf, beta, logits);
}

// Round 9
// 235.237 us; speedup vs baseline: 4.0218x; 1.5108x over previous
//
#include <hip/hip_runtime.h>
#include <hip/hip_bf16.h>
#include <stdint.h>

// Sizes: BS=64, M=1000, CLIP=512, D=512, N_WAYS=20, N_Z=8
// out = [logits (8,64,1000,20) | z (8,64,20,512) | mu (64,20,512) | scale (64,20,512)]

typedef __attribute__((ext_vector_type(8))) short short8;
typedef __attribute__((ext_vector_type(4))) float f32x4;

__device__ __forceinline__ float gelu_f(float x) {
    return 0.5f * x * (1.0f + erff(x * 0.70710678118654752440f));
}
__device__ __forceinline__ float softplus_f(float x) {
    return fmaxf(x, 0.0f) + log1pf(expf(-fabsf(x)));
}
__device__ __forceinline__ uint32_t cvt2(float a, float b) {  // pack 2 bf16 (RNE)
    __hip_bfloat162 h;
    h.x = __float2bfloat16(a);
    h.y = __float2bfloat16(b);
    uint32_t u; __builtin_memcpy(&u, &h, 4); return u;
}
__device__ __forceinline__ unsigned short f2bfu(float f) {
    __hip_bfloat16 h = __float2bfloat16(f);
    unsigned short u; __builtin_memcpy(&u, &h, 2); return u;
}
__device__ __forceinline__ float bfu2f(unsigned short u) {
    uint32_t v = (uint32_t)u << 16; float f; __builtin_memcpy(&f, &v, 4); return f;
}

// ---------------- threefry2x32 (partitionable) ----------------
__device__ __forceinline__ void threefry2x32(uint32_t k0, uint32_t k1,
                                             uint32_t x0, uint32_t x1,
                                             uint32_t& o0, uint32_t& o1) {
    uint32_t ks[3] = {k0, k1, k0 ^ k1 ^ 0x1BD11BDAu};
    x0 += ks[0]; x1 += ks[1];
    const uint32_t rot[8] = {13,15,26,6,17,29,16,24};
#pragma unroll
    for (int i = 0; i < 5; i++) {
#pragma unroll
        for (int j = 0; j < 4; j++) {
            uint32_t r = rot[(i & 1) * 4 + j];
            x0 += x1;
            x1 = (x1 << r) | (x1 >> (32 - r));
            x1 ^= x0;
        }
        x0 += ks[(i + 1) % 3];
        x1 += ks[(i + 2) % 3] + (uint32_t)(i + 1);
    }
    o0 = x0; o1 = x1;
}

__device__ __forceinline__ float bits_to_normal(uint32_t b) {
    float f = __uint_as_float((b >> 9) | 0x3F800000u) - 1.0f;
    const float lo = __uint_as_float(0xBF7FFFFFu);
    float u = fmaxf(lo, f * 2.0f + lo);
    return 1.41421356237309504880f * erfinvf(u);
}

// ---------------- K1: class scatter partials, software-pipelined ----------------
__global__ __launch_bounds__(512) void scatter_k(const float* __restrict__ xc,
                                                 const int* __restrict__ y,
                                                 float* __restrict__ Apart,
                                                 float* __restrict__ cntpart) {
    __shared__ float sA[20 * 512];
    __shared__ float scnt[20];
    const int b = blockIdx.x, ch = blockIdx.y;
    const int tid = threadIdx.x;
    for (int i = tid; i < 20 * 512; i += 512) sA[i] = 0.f;
    if (tid < 20) scnt[tid] = 0.f;
    __syncthreads();
    const int m0 = ch * 125;
    const size_t xbase = ((size_t)b * 1000 + m0) * 512 + tid;
    const int ybase = b * 1000 + m0;

    float xv[8]; int cv[8];
#pragma unroll
    for (int j = 0; j < 8; j++) {
        xv[j] = xc[xbase + (size_t)j * 512];
        cv[j] = y[ybase + j];
    }
    int p = 8;
    for (int pan = 0; pan < 15; pan++) {
        float xn[8]; int cn[8];
        const bool more = (pan < 14);
        if (more) {
#pragma unroll
            for (int j = 0; j < 8; j++) {
                xn[j] = xc[xbase + (size_t)(p + j) * 512];
                cn[j] = y[ybase + p + j];
            }
        }
#pragma unroll
        for (int j = 0; j < 8; j++) {
            sA[cv[j] * 512 + tid] += xv[j];
            if (tid == 0) scnt[cv[j]] += 1.f;
        }
        if (more) {
#pragma unroll
            for (int j = 0; j < 8; j++) { xv[j] = xn[j]; cv[j] = cn[j]; }
            p += 8;
        }
    }
#pragma unroll
    for (int j = 0; j < 5; j++) {
        float xx = xc[xbase + (size_t)(120 + j) * 512];
        int cc = y[ybase + 120 + j];
        sA[cc * 512 + tid] += xx;
        if (tid == 0) scnt[cc] += 1.f;
    }
    __syncthreads();
    float* dst = Apart + (size_t)ch * 655360 + (size_t)b * 10240;
    for (int i = tid; i < 10240; i += 512) dst[i] = sA[i];
    if (tid < 20) cntpart[(size_t)ch * 1280 + b * 20 + tid] = scnt[tid];
}

// ---------------- K2: fixed-order reduce -> bf16 A + fp32 cnt ----------------
__global__ __launch_bounds__(256) void reduce_bf_k(const float* __restrict__ Apart,
                                                   const float* __restrict__ cntpart,
                                                   unsigned short* __restrict__ Abf,
                                                   float* __restrict__ cnt) {
    int i = blockIdx.x * 256 + threadIdx.x;   // grid 640 -> 163840 float4 groups
    if (i < 163840) {
        const float4* Ap4 = (const float4*)Apart;
        float4 s = Ap4[i];
#pragma unroll
        for (int p = 1; p < 8; p++) {
            float4 v = Ap4[(size_t)p * 163840 + i];
            s.x += v.x; s.y += v.y; s.z += v.z; s.w += v.w;
        }
        uint2 o;
        o.x = cvt2(s.x, s.y); o.y = cvt2(s.z, s.w);
        *(uint2*)&Abf[(size_t)i * 4] = o;
    }
    if (i < 1280) {
        float s = 0.f;
#pragma unroll
        for (int p = 0; p < 8; p++) s += cntpart[p * 1280 + i];
        cnt[i] = s;
    }
}

// ---------------- generic transpose: src fp32 [R x C] -> dst bf16 [C x R] ----
__global__ __launch_bounds__(256) void wtg_k(const float* __restrict__ src,
                                             unsigned short* __restrict__ dst,
                                             int R, int C) {
    __shared__ float T[64][65];
    const int r0 = blockIdx.y * 64, c0 = blockIdx.x * 64;
    const int tid = threadIdx.x;
    const int rr = tid >> 4, cc = (tid & 15) * 4;
#pragma unroll
    for (int l = 0; l < 4; l++) {
        int row = rr + l * 16;
        float4 v = *(const float4*)&src[(size_t)(r0 + row) * C + c0 + cc];
        T[row][cc] = v.x; T[row][cc+1] = v.y; T[row][cc+2] = v.z; T[row][cc+3] = v.w;
    }
    __syncthreads();
#pragma unroll
    for (int l = 0; l < 4; l++) {
        int n = rr + l * 16;
        uint2 u;
        u.x = cvt2(T[cc][n], T[cc+1][n]);
        u.y = cvt2(T[cc+2][n], T[cc+3][n]);
        *(uint2*)&dst[(size_t)(c0 + n) * R + r0 + cc] = u;
    }
}

// ---------------- plain bf16 convert (Wp for step 9) ----------------
__global__ __launch_bounds__(256) void wconv_k(const float* __restrict__ in,
                                               unsigned short* __restrict__ o, int n2) {
    int i = blockIdx.x * 256 + threadIdx.x;
    if (i < n2) {
        float2 v = *(const float2*)&in[i * 2];
        *(uint32_t*)&o[i * 2] = cvt2(v.x, v.y);
    }
}

// ---------------- unified bf16 MFMA GEMM, 64x128 tile, K=512 ----------------
// A: bf16 [M x 512]; B: bf16 [Nn x 512] (row n = output col n).
// EPI 0: C0 = acc + bias (bf16)        EPI 1: C0 = relu(acc + extra[r]*bias[c]) (bf16)
// EPI 2: C0 = gelu(acc + bias) (bf16)  EPI 3: Nn=1024 split -> F0 = mu (f32), F1 = 0.01+0.99*softplus (f32)
template <int EPI>
__global__ __launch_bounds__(256) void gm2_k(const unsigned short* __restrict__ Abf,
                                             const unsigned short* __restrict__ Bbf,
                                             const float* __restrict__ bias,
                                             const float* __restrict__ extra,
                                             unsigned short* __restrict__ C0,
                                             float* __restrict__ F0,
                                             float* __restrict__ F1,
                                             int Nn) {
    __shared__ unsigned short As[64 * 64];    // 8 KB, XOR-swizzled
    __shared__ unsigned short Bs[128 * 64];   // 16 KB
    const int tid = threadIdx.x;
    const int lane = tid & 63, w = tid >> 6;
    const int row0 = blockIdx.y * 64, col0 = blockIdx.x * 128;
    f32x4 acc[4][2] = {};
    for (int k0 = 0; k0 < 512; k0 += 64) {
        {   // stage A (64 rows x 64 k)
            int row = tid >> 2, cs = (tid & 3) * 16;
            int swz = (row & 7) << 4;
            const unsigned short* src = Abf + (size_t)(row0 + row) * 512 + k0 + cs;
#pragma unroll
            for (int j = 0; j < 2; j++) {
                uint4 u = *(const uint4*)(src + j * 8);
                *(uint4*)((char*)As + row * 128 + (((cs + j * 8) * 2) ^ swz)) = u;
            }
        }
        {   // stage B (128 rows x 64 k)
            int row = tid >> 1, cs = (tid & 1) * 32;
            int swz = (row & 7) << 4;
            const unsigned short* src = Bbf + (size_t)(col0 + row) * 512 + k0 + cs;
#pragma unroll
            for (int j = 0; j < 4; j++) {
                uint4 u = *(const uint4*)(src + j * 8);
                *(uint4*)((char*)Bs + row * 128 + (((cs + j * 8) * 2) ^ swz)) = u;
            }
        }
        __syncthreads();
#pragma unroll
        for (int ks = 0; ks < 2; ks++) {
            short8 a[4], bb[2];
#pragma unroll
            for (int mi = 0; mi < 4; mi++) {
                int r = mi * 16 + (lane & 15);
                a[mi] = *(const short8*)((const char*)As + r * 128 +
                          (((ks * 32 + (lane >> 4) * 8) * 2) ^ ((r & 7) << 4)));
            }
#pragma unroll
            for (int ni = 0; ni < 2; ni++) {
                int n = w * 32 + ni * 16 + (lane & 15);
                bb[ni] = *(const short8*)((const char*)Bs + n * 128 +
                          (((ks * 32 + (lane >> 4) * 8) * 2) ^ ((n & 7) << 4)));
            }
#pragma unroll
            for (int mi = 0; mi < 4; mi++)
#pragma unroll
                for (int ni = 0; ni < 2; ni++)
                    acc[mi][ni] = __builtin_amdgcn_mfma_f32_16x16x32_bf16(a[mi], bb[ni], acc[mi][ni], 0, 0, 0);
        }
        __syncthreads();
    }
#pragma unroll
    for (int mi = 0; mi < 4; mi++) {
#pragma unroll
        for (int ni = 0; ni < 2; ni++) {
            int c = col0 + w * 32 + ni * 16 + (lane & 15);
            float bv = bias ? bias[c] : 0.f;
#pragma unroll
            for (int j = 0; j < 4; j++) {
                int r = row0 + mi * 16 + (lane >> 4) * 4 + j;
                float v = acc[mi][ni][j];
                if (EPI == 0) {
                    v += bv;
                    C0[(size_t)r * Nn + c] = f2bfu(v);
                } else if (EPI == 1) {
                    v += extra[r] * bv;
                    C0[(size_t)r * Nn + c] = f2bfu(fmaxf(v, 0.f));
                } else if (EPI == 2) {
                    C0[(size_t)r * Nn + c] = f2bfu(gelu_f(v + bv));
                } else {
                    v += bv;
                    if (c < 512) F0[(size_t)r * 512 + c] = v;
                    else F1[(size_t)r * 512 + (c - 512)] = 0.01f + 0.99f * softplus_f(v);
                }
            }
        }
    }
}

// ---------------- z = mu + scale*eps ; emits fp32 z + bf16 zb ----------------
__global__ __launch_bounds__(256) void z2_k(const float* __restrict__ mu,
                                            const float* __restrict__ sc,
                                            float* __restrict__ z,
                                            unsigned short* __restrict__ zb) {
    const uint32_t NH = 2621440u;  // 5242880/2
    uint32_t i = blockIdx.x * 256u + threadIdx.x;
    if (i >= NH) return;
    uint32_t t0 = 2u * i;
    uint32_t o0, o1, p0, p1;
    threefry2x32(0u, 42u, 0u, t0, o0, o1);
    threefry2x32(0u, 42u, 0u, t0 + 1u, p0, p1);
    uint32_t r0 = t0 % 655360u;                  // even; r1 = r0+1 (no wrap)
    float2 mv = *(const float2*)&mu[r0];
    float2 sv = *(const float2*)&sc[r0];
    float z0 = mv.x + sv.x * bits_to_normal(o0 ^ o1);
    float z1 = mv.y + sv.y * bits_to_normal(p0 ^ p1);
    float2 zo; zo.x = z0; zo.y = z1;
    *(float2*)&z[t0] = zo;
    *(uint32_t*)&zb[t0] = cvt2(z0, z1);
}

// ---------------- beta[r] = dot(bp, Wf_bf[r,:]) ----------------
__global__ __launch_bounds__(256) void beta_bf_k(const unsigned short* __restrict__ Wfb,
                                                 const float* __restrict__ bp,
                                                 float* __restrict__ beta) {
    int wave = threadIdx.x >> 6, lane = threadIdx.x & 63;
    int r = blockIdx.x * 4 + wave;
    short8 wv = *(const short8*)(Wfb + (size_t)r * 512 + lane * 8);
    float s = 0.f;
#pragma unroll
    for (int e = 0; e < 8; e++) s += bp[lane * 8 + e] * bfu2f((unsigned short)wv[e]);
#pragma unroll
    for (int o = 32; o > 0; o >>= 1) s += __shfl_down(s, o, 64);
    if (lane == 0) beta[r] = s;
}

// ---------------- logits v3: one block = 128 q x ALL 160 (s,n) rows ----------
__global__ __launch_bounds__(512) void logits_mfma3_k(const float* __restrict__ Xq,
                                                      const unsigned short* __restrict__ Vb,
                                                      const float* __restrict__ beta,
                                                      float* __restrict__ out) {
    __shared__ unsigned short Vs[160 * 64];  // 20 KB
    __shared__ float bs[160];
    const int u = blockIdx.x + 8 * blockIdx.y;
    const int xcd = u & 7, idx = u >> 3;
    const int b = (idx & 7) * 8 + xcd;
    const int qh = idx >> 3;
    const int tid = threadIdx.x, lane = tid & 63, w = tid >> 6;
    const int wq = w >> 1, wn = w & 1;

    if (tid < 160) {
        int s = tid / 20, n = tid - s * 20;
        bs[tid] = beta[(size_t)(s * 64 + b) * 20 + n];
    }

    const int klane = (lane >> 4) * 8;
    const float* xp[2];
    int qb[2];
#pragma unroll
    for (int qs = 0; qs < 2; qs++) {
        qb[qs] = qh * 128 + wq * 32 + qs * 16;
        int qr = qb[qs] + (lane & 15);
        if (qr > 999) qr = 999;
        xp[qs] = Xq + ((size_t)b * 1000 + qr) * 512 + klane;
    }
    int vrow[5], vswz[5];
#pragma unroll
    for (int nf = 0; nf < 5; nf++) {
        int rr = wn * 80 + nf * 16 + (lane & 15);
        vrow[nf] = rr * 128;
        vswz[nf] = (rr & 7) << 4;
    }

    f32x4 acc[2][5] = {};
    for (int k0 = 0; k0 < 512; k0 += 64) {
        __syncthreads();
        for (int c = tid; c < 640; c += 512) {
            int row = c >> 2, off = (c & 3) * 32;
            int sdiv = row / 20;
            int row_g = row + sdiv * 1260 + b * 20;
            const unsigned short* src = Vb + (size_t)row_g * 512 + k0 + (c & 3) * 16;
            uint4 u0 = *(const uint4*)src;
            uint4 u1 = *(const uint4*)(src + 8);
            int swz = (row & 7) << 4;
            char* base = (char*)Vs + row * 128;
            *(uint4*)(base + (off ^ swz)) = u0;
            *(uint4*)(base + ((off + 16) ^ swz)) = u1;
        }
        __syncthreads();
#pragma unroll
        for (int ks = 0; ks < 2; ks++) {
            int kb = (ks * 32 + klane) * 2;
            short8 bf[5];
#pragma unroll
            for (int nf = 0; nf < 5; nf++)
                bf[nf] = *(const short8*)((const char*)Vs + vrow[nf] + (kb ^ vswz[nf]));
            short8 af[2];
#pragma unroll
            for (int qs = 0; qs < 2; qs++) {
                const float* p = xp[qs] + k0 + ks * 32;
                float4 v0 = *(const float4*)p;
                float4 v1 = *(const float4*)(p + 4);
                uint4 uu;
                uu.x = cvt2(v0.x, v0.y); uu.y = cvt2(v0.z, v0.w);
                uu.z = cvt2(v1.x, v1.y); uu.w = cvt2(v1.z, v1.w);
                __builtin_memcpy(&af[qs], &uu, 16);
            }
#pragma unroll
            for (int qs = 0; qs < 2; qs++)
#pragma unroll
                for (int nf = 0; nf < 5; nf++)
                    acc[qs][nf] = __builtin_amdgcn_mfma_f32_16x16x32_bf16(af[qs], bf[nf], acc[qs][nf], 0, 0, 0);
        }
    }

#pragma unroll
    for (int nf = 0; nf < 5; nf++) {
        int rl = wn * 80 + nf * 16 + (lane & 15);
        int s = rl / 20, n = rl - s * 20;
        float bb = bs[rl];
        size_t ob = (size_t)(s * 64 + b) * 20000;
#pragma unroll
        for (int qs = 0; qs < 2; qs++) {
#pragma unroll
            for (int j = 0; j < 4; j++) {
                int q = qb[qs] + (lane >> 4) * 4 + j;
                if (q < 1000)
                    out[ob + (size_t)q * 20 + n] = acc[qs][nf][j] + bb;
            }
        }
    }
}

extern "C" void kernel_launch(void* const* d_in, const int* in_sizes, int n_in,
                              void* d_out, int out_size, void* d_ws, size_t ws_size,
                              hipStream_t stream) {
    const float* x_context = (const float*)d_in[0];
    const int*   y_context = (const int*)d_in[1];
    const float* x_query   = (const float*)d_in[2];
    const float* Wp  = (const float*)d_in[3];
    const float* bp  = (const float*)d_in[4];
    const float* Wa1 = (const float*)d_in[5];
    const float* ba1 = (const float*)d_in[6];
    const float* Wa2 = (const float*)d_in[7];
    const float* ba2 = (const float*)d_in[8];
    const float* Wd1 = (const float*)d_in[9];
    const float* bd1 = (const float*)d_in[10];
    const float* Wd2 = (const float*)d_in[11];
    const float* bd2 = (const float*)d_in[12];

    float* out    = (float*)d_out;
    float* logits = out;                   // 10,240,000 f
    float* z      = out + 10240000;        // 5,242,880 f
    float* mu     = out + 15482880;        // 655,360 f
    float* sc     = out + 16138240;        // 655,360 f
    unsigned short* Wfb = (unsigned short*)d_out;  // bf16 Wf scratch in logits region

    // workspace layout
    float* ws   = (float*)d_ws;
    float* cnt  = ws;                       // 1,280 f
    float* beta = cnt + 1280;               // 10,240 f
    unsigned short* WpTb  = (unsigned short*)(beta + 10240);  // 262,144 sh
    unsigned short* Wa1Tb = WpTb + 262144;                    // 262,144 sh
    unsigned short* Wa2Tb = Wa1Tb + 262144;                   // 524,288 sh
    unsigned short* WdT1b = Wa2Tb + 524288;                   // 262,144 sh
    unsigned short* WdT2b = WdT1b + 262144;                   // 262,144 sh
    unsigned short* Wpb   = WdT2b + 262144;                   // 262,144 sh
    unsigned short* Abf   = Wpb + 262144;                     // 655,360 sh
    unsigned short* combb = Abf + 655360;                     // 655,360 sh
    unsigned short* hb    = combb + 655360;                   // 655,360 sh
    unsigned short* zb    = hb + 655360;                      // 5,242,880 sh
    unsigned short* Vbf   = zb + 5242880;                     // 5,242,880 sh
    float* big = (float*)(Vbf + 5242880);                     // 5,242,880 f : Apart -> Wgb
    unsigned short* Wgb = (unsigned short*)big;

    // 0) weight prep (independent; overlap)
    wtg_k<<<dim3(8, 8), 256, 0, stream>>>(Wp,  WpTb,  512, 512);
    wtg_k<<<dim3(8, 8), 256, 0, stream>>>(Wa1, Wa1Tb, 512, 512);
    wtg_k<<<dim3(16, 8), 256, 0, stream>>>(Wa2, Wa2Tb, 512, 1024);
    wtg_k<<<dim3(8, 8), 256, 0, stream>>>(Wd1, WdT1b, 512, 512);
    wtg_k<<<dim3(8, 8), 256, 0, stream>>>(Wd2, WdT2b, 512, 512);
    wconv_k<<<dim3(512), 256, 0, stream>>>(Wp, Wpb, 131072);
    // 1-2) scatter + reduce -> Abf (bf16 1280x512), cnt
    scatter_k<<<dim3(64, 8), 512, 0, stream>>>(x_context, y_context, big /*Apart*/, beta /*cntpart*/);
    reduce_bf_k<<<dim3(640), 256, 0, stream>>>(big, beta, Abf, cnt);
    // 3) comb = relu(A@Wp + cnt*bp)      [MFMA bf16]
    gm2_k<1><<<dim3(4, 20), 256, 0, stream>>>(Abf, WpTb, bp, cnt, combb, nullptr, nullptr, 512);
    // 4) h = gelu(comb@Wa1 + ba1)        [MFMA bf16]
    gm2_k<2><<<dim3(4, 20), 256, 0, stream>>>(combb, Wa1Tb, ba1, nullptr, hb, nullptr, nullptr, 512);
    // 5) stats = h@Wa2 + ba2 -> mu, scale (fp32 outputs)
    gm2_k<3><<<dim3(8, 20), 256, 0, stream>>>(hb, Wa2Tb, ba2, nullptr, nullptr, mu, sc, 1024);
    // 6) z (fp32 out) + zb (bf16)
    z2_k<<<dim3(10240), 256, 0, stream>>>(mu, sc, z, zb);
    // 7) Wg_bf = gelu(z@Wd1 + bd1)
    gm2_k<2><<<dim3(4, 160), 256, 0, stream>>>(zb, WdT1b, bd1, nullptr, Wgb, nullptr, nullptr, 512);
    // 8) Wf_bf = Wg@Wd2 + bd2  (into d_out logits region)
    gm2_k<0><<<dim3(4, 160), 256, 0, stream>>>(Wgb, WdT2b, bd2, nullptr, Wfb, nullptr, nullptr, 512);
    // 9) V_bf = Wf @ Wp^T
    gm2_k<0><<<dim3(4, 160), 256, 0, stream>>>(Wfb, Wpb, nullptr, nullptr, Vbf, nullptr, nullptr, 512);
    // 10) beta
    beta_bf_k<<<dim3(2560), 256, 0, stream>>>(Wfb, bp, beta);
    // 11) logits (overwrites Wf region last)
    logits_mfma3_k<<<dim3(8, 64), 512, 0, stream>>>(x_query, Vbf, beta, logits);
}

// Round 10
// 229.436 us; speedup vs baseline: 4.1235x; 1.0253x over previous
//
#include <hip/hip_runtime.h>
#include <hip/hip_bf16.h>
#include <stdint.h>

// Sizes: BS=64, M=1000, CLIP=512, D=512, N_WAYS=20, N_Z=8
// out = [logits (8,64,1000,20) | z (8,64,20,512) | mu (64,20,512) | scale (64,20,512)]

typedef __attribute__((ext_vector_type(8))) short short8;
typedef __attribute__((ext_vector_type(4))) float f32x4;

__device__ __forceinline__ float gelu_f(float x) {
    return 0.5f * x * (1.0f + erff(x * 0.70710678118654752440f));
}
__device__ __forceinline__ float softplus_f(float x) {
    return fmaxf(x, 0.0f) + log1pf(expf(-fabsf(x)));
}
__device__ __forceinline__ uint32_t cvt2(float a, float b) {  // pack 2 bf16 (RNE)
    __hip_bfloat162 h;
    h.x = __float2bfloat16(a);
    h.y = __float2bfloat16(b);
    uint32_t u; __builtin_memcpy(&u, &h, 4); return u;
}
__device__ __forceinline__ unsigned short f2bfu(float f) {
    __hip_bfloat16 h = __float2bfloat16(f);
    unsigned short u; __builtin_memcpy(&u, &h, 2); return u;
}
__device__ __forceinline__ float bfu2f(unsigned short u) {
    uint32_t v = (uint32_t)u << 16; float f; __builtin_memcpy(&f, &v, 4); return f;
}

// ---------------- threefry2x32 (partitionable) ----------------
__device__ __forceinline__ void threefry2x32(uint32_t k0, uint32_t k1,
                                             uint32_t x0, uint32_t x1,
                                             uint32_t& o0, uint32_t& o1) {
    uint32_t ks[3] = {k0, k1, k0 ^ k1 ^ 0x1BD11BDAu};
    x0 += ks[0]; x1 += ks[1];
    const uint32_t rot[8] = {13,15,26,6,17,29,16,24};
#pragma unroll
    for (int i = 0; i < 5; i++) {
#pragma unroll
        for (int j = 0; j < 4; j++) {
            uint32_t r = rot[(i & 1) * 4 + j];
            x0 += x1;
            x1 = (x1 << r) | (x1 >> (32 - r));
            x1 ^= x0;
        }
        x0 += ks[(i + 1) % 3];
        x1 += ks[(i + 2) % 3] + (uint32_t)(i + 1);
    }
    o0 = x0; o1 = x1;
}

__device__ __forceinline__ float bits_to_normal(uint32_t b) {
    float f = __uint_as_float((b >> 9) | 0x3F800000u) - 1.0f;
    const float lo = __uint_as_float(0xBF7FFFFFu);
    float u = fmaxf(lo, f * 2.0f + lo);
    return 1.41421356237309504880f * erfinvf(u);
}

// ---------------- batched prep: transposes, convs, dots, c0, counts -----------
// flat block id:
// [0,64)   WpT   [64,128) Wa1T   [128,256) Wa2T(C=1024)   [256,320) Wd1T
// [320,448) conv Wp -> Wpb   [448,576) conv Wd2 -> Wd2b
// [576,704) bv[d]=Wp[d,:]·bd2   [704,832) w2bp[k]=Wd2[k,:]·bp
// [832] c0 = bp·bd2            [833,897) cnt[b,cls]
__global__ __launch_bounds__(256) void prep_k(
    const float* __restrict__ Wp, const float* __restrict__ Wa1,
    const float* __restrict__ Wa2, const float* __restrict__ Wd1,
    const float* __restrict__ Wd2, const float* __restrict__ bp,
    const float* __restrict__ bd2, const int* __restrict__ y,
    unsigned short* __restrict__ WpTb, unsigned short* __restrict__ Wa1Tb,
    unsigned short* __restrict__ Wa2Tb, unsigned short* __restrict__ WdT1b,
    unsigned short* __restrict__ Wpb, unsigned short* __restrict__ Wd2b,
    float* __restrict__ bv, float* __restrict__ w2bp,
    float* __restrict__ c0, float* __restrict__ cnt)
{
    __shared__ float T[64][65];
    __shared__ int lc[32];
    __shared__ float ws4[4];
    const int f = blockIdx.x;
    const int tid = threadIdx.x;

    if (f < 320) {  // ---- transpose fp32 [512 x C] -> bf16 [C x 512]
        const float* src; unsigned short* dst; int C, t, xb, yb;
        if (f < 64)       { src = Wp;  dst = WpTb;  C = 512;  t = f;       xb = t & 7;  yb = t >> 3; }
        else if (f < 128) { src = Wa1; dst = Wa1Tb; C = 512;  t = f - 64;  xb = t & 7;  yb = t >> 3; }
        else if (f < 256) { src = Wa2; dst = Wa2Tb; C = 1024; t = f - 128; xb = t & 15; yb = t >> 4; }
        else              { src = Wd1; dst = WdT1b; C = 512;  t = f - 256; xb = t & 7;  yb = t >> 3; }
        const int r0 = yb * 64, cc0 = xb * 64;
        const int rr = tid >> 4, cc = (tid & 15) * 4;
#pragma unroll
        for (int l = 0; l < 4; l++) {
            int row = rr + l * 16;
            float4 v = *(const float4*)&src[(size_t)(r0 + row) * C + cc0 + cc];
            T[row][cc] = v.x; T[row][cc+1] = v.y; T[row][cc+2] = v.z; T[row][cc+3] = v.w;
        }
        __syncthreads();
#pragma unroll
        for (int l = 0; l < 4; l++) {
            int n = rr + l * 16;
            uint2 u;
            u.x = cvt2(T[cc][n], T[cc+1][n]);
            u.y = cvt2(T[cc+2][n], T[cc+3][n]);
            *(uint2*)&dst[(size_t)(cc0 + n) * 512 + r0 + cc] = u;
        }
    } else if (f < 576) {  // ---- plain conv fp32 -> bf16 (8 floats/thread)
        const float* src = (f < 448) ? Wp : Wd2;
        unsigned short* dst = (f < 448) ? Wpb : Wd2b;
        int t = (f < 448) ? f - 320 : f - 448;
        size_t i = ((size_t)t * 256 + tid) * 8;    // float index, 8 per thread
        float4 a = *(const float4*)&src[i];
        float4 b4 = *(const float4*)&src[i + 4];
        uint4 u;
        u.x = cvt2(a.x, a.y);  u.y = cvt2(a.z, a.w);
        u.z = cvt2(b4.x, b4.y); u.w = cvt2(b4.z, b4.w);
        *(uint4*)&dst[i] = u;
    } else if (f < 832) {  // ---- row dots (wave per row)
        const float* W = (f < 704) ? Wp : Wd2;
        const float* v = (f < 704) ? bd2 : bp;
        float* o = (f < 704) ? bv : w2bp;
        int t = (f < 704) ? f - 576 : f - 704;
        int wave = tid >> 6, lane = tid & 63;
        int r = t * 4 + wave;
        const float* row = W + (size_t)r * 512 + lane * 8;
        float4 x0 = *(const float4*)row;
        float4 x1 = *(const float4*)(row + 4);
        float4 v0 = *(const float4*)&v[lane * 8];
        float4 v1 = *(const float4*)&v[lane * 8 + 4];
        float s = x0.x*v0.x + x0.y*v0.y + x0.z*v0.z + x0.w*v0.w
                + x1.x*v1.x + x1.y*v1.y + x1.z*v1.z + x1.w*v1.w;
#pragma unroll
        for (int off = 32; off > 0; off >>= 1) s += __shfl_down(s, off, 64);
        if (lane == 0) o[r] = s;
    } else if (f == 832) {  // ---- c0 = bp . bd2
        float s = bp[tid] * bd2[tid] + bp[tid + 256] * bd2[tid + 256];
#pragma unroll
        for (int off = 32; off > 0; off >>= 1) s += __shfl_down(s, off, 64);
        int wave = tid >> 6, lane = tid & 63;
        if (lane == 0) ws4[wave] = s;
        __syncthreads();
        if (tid == 0) c0[0] = ws4[0] + ws4[1] + ws4[2] + ws4[3];
    } else {  // ---- class counts, exact int atomics
        int b = f - 833;
        if (tid < 32) lc[tid] = 0;
        __syncthreads();
        for (int m = tid; m < 1000; m += 256)
            atomicAdd(&lc[y[b * 1000 + m]], 1);
        __syncthreads();
        if (tid < 20) cnt[b * 20 + tid] = (float)lc[tid];
    }
}

// ---------------- K1: class scatter partials, software-pipelined ----------------
__global__ __launch_bounds__(512) void scatter_k(const float* __restrict__ xc,
                                                 const int* __restrict__ y,
                                                 float* __restrict__ Apart) {
    __shared__ float sA[20 * 512];
    const int b = blockIdx.x, ch = blockIdx.y;
    const int tid = threadIdx.x;
    for (int i = tid; i < 20 * 512; i += 512) sA[i] = 0.f;
    __syncthreads();
    const int m0 = ch * 125;
    const size_t xbase = ((size_t)b * 1000 + m0) * 512 + tid;
    const int ybase = b * 1000 + m0;

    float xv[8]; int cv[8];
#pragma unroll
    for (int j = 0; j < 8; j++) {
        xv[j] = xc[xbase + (size_t)j * 512];
        cv[j] = y[ybase + j];
    }
    int p = 8;
    for (int pan = 0; pan < 15; pan++) {
        float xn[8]; int cn[8];
        const bool more = (pan < 14);
        if (more) {
#pragma unroll
            for (int j = 0; j < 8; j++) {
                xn[j] = xc[xbase + (size_t)(p + j) * 512];
                cn[j] = y[ybase + p + j];
            }
        }
#pragma unroll
        for (int j = 0; j < 8; j++) sA[cv[j] * 512 + tid] += xv[j];
        if (more) {
#pragma unroll
            for (int j = 0; j < 8; j++) { xv[j] = xn[j]; cv[j] = cn[j]; }
            p += 8;
        }
    }
#pragma unroll
    for (int j = 0; j < 5; j++) {
        float xx = xc[xbase + (size_t)(120 + j) * 512];
        int cc = y[ybase + 120 + j];
        sA[cc * 512 + tid] += xx;
    }
    __syncthreads();
    float* dst = Apart + (size_t)ch * 655360 + (size_t)b * 10240;
    for (int i = tid; i < 10240; i += 512) dst[i] = sA[i];
}

// ---------------- K2: fixed-order reduce -> bf16 A ----------------
__global__ __launch_bounds__(256) void reduce_bf_k(const float* __restrict__ Apart,
                                                   unsigned short* __restrict__ Abf) {
    int i = blockIdx.x * 256 + threadIdx.x;   // grid 640 -> 163840 float4 groups
    if (i < 163840) {
        const float4* Ap4 = (const float4*)Apart;
        float4 s = Ap4[i];
#pragma unroll
        for (int p = 1; p < 8; p++) {
            float4 v = Ap4[(size_t)p * 163840 + i];
            s.x += v.x; s.y += v.y; s.z += v.z; s.w += v.w;
        }
        uint2 o;
        o.x = cvt2(s.x, s.y); o.y = cvt2(s.z, s.w);
        *(uint2*)&Abf[(size_t)i * 4] = o;
    }
}

// ---------------- unified bf16 MFMA GEMM, 64x128 tile, K=512 ----------------
// A: bf16 [M x 512]; B: bf16 [Nn x 512] (row n = output col n).
// EPI 0: C0 = acc + bias (bf16)        EPI 1: C0 = relu(acc + extra[r]*bias[c]) (bf16)
// EPI 2: C0 = gelu(acc + bias) (bf16)  EPI 3: Nn=1024 split -> F0 = mu (f32), F1 = 0.01+0.99*softplus (f32)
template <int EPI>
__global__ __launch_bounds__(256) void gm2_k(const unsigned short* __restrict__ Abf,
                                             const unsigned short* __restrict__ Bbf,
                                             const float* __restrict__ bias,
                                             const float* __restrict__ extra,
                                             unsigned short* __restrict__ C0,
                                             float* __restrict__ F0,
                                             float* __restrict__ F1,
                                             int Nn) {
    __shared__ unsigned short As[64 * 64];    // 8 KB, XOR-swizzled
    __shared__ unsigned short Bs[128 * 64];   // 16 KB
    const int tid = threadIdx.x;
    const int lane = tid & 63, w = tid >> 6;
    const int row0 = blockIdx.y * 64, col0 = blockIdx.x * 128;
    f32x4 acc[4][2] = {};
    for (int k0 = 0; k0 < 512; k0 += 64) {
        {   // stage A (64 rows x 64 k)
            int row = tid >> 2, cs = (tid & 3) * 16;
            int swz = (row & 7) << 4;
            const unsigned short* src = Abf + (size_t)(row0 + row) * 512 + k0 + cs;
#pragma unroll
            for (int j = 0; j < 2; j++) {
                uint4 u = *(const uint4*)(src + j * 8);
                *(uint4*)((char*)As + row * 128 + (((cs + j * 8) * 2) ^ swz)) = u;
            }
        }
        {   // stage B (128 rows x 64 k)
            int row = tid >> 1, cs = (tid & 1) * 32;
            int swz = (row & 7) << 4;
            const unsigned short* src = Bbf + (size_t)(col0 + row) * 512 + k0 + cs;
#pragma unroll
            for (int j = 0; j < 4; j++) {
                uint4 u = *(const uint4*)(src + j * 8);
                *(uint4*)((char*)Bs + row * 128 + (((cs + j * 8) * 2) ^ swz)) = u;
            }
        }
        __syncthreads();
#pragma unroll
        for (int ks = 0; ks < 2; ks++) {
            short8 a[4], bb[2];
#pragma unroll
            for (int mi = 0; mi < 4; mi++) {
                int r = mi * 16 + (lane & 15);
                a[mi] = *(const short8*)((const char*)As + r * 128 +
                          (((ks * 32 + (lane >> 4) * 8) * 2) ^ ((r & 7) << 4)));
            }
#pragma unroll
            for (int ni = 0; ni < 2; ni++) {
                int n = w * 32 + ni * 16 + (lane & 15);
                bb[ni] = *(const short8*)((const char*)Bs + n * 128 +
                          (((ks * 32 + (lane >> 4) * 8) * 2) ^ ((n & 7) << 4)));
            }
#pragma unroll
            for (int mi = 0; mi < 4; mi++)
#pragma unroll
                for (int ni = 0; ni < 2; ni++)
                    acc[mi][ni] = __builtin_amdgcn_mfma_f32_16x16x32_bf16(a[mi], bb[ni], acc[mi][ni], 0, 0, 0);
        }
        __syncthreads();
    }
#pragma unroll
    for (int mi = 0; mi < 4; mi++) {
#pragma unroll
        for (int ni = 0; ni < 2; ni++) {
            int c = col0 + w * 32 + ni * 16 + (lane & 15);
            float bv = bias ? bias[c] : 0.f;
#pragma unroll
            for (int j = 0; j < 4; j++) {
                int r = row0 + mi * 16 + (lane >> 4) * 4 + j;
                float v = acc[mi][ni][j];
                if (EPI == 0) {
                    v += bv;
                    C0[(size_t)r * Nn + c] = f2bfu(v);
                } else if (EPI == 1) {
                    v += extra[r] * bv;
                    C0[(size_t)r * Nn + c] = f2bfu(fmaxf(v, 0.f));
                } else if (EPI == 2) {
                    C0[(size_t)r * Nn + c] = f2bfu(gelu_f(v + bv));
                } else {
                    v += bv;
                    if (c < 512) F0[(size_t)r * 512 + c] = v;
                    else F1[(size_t)r * 512 + (c - 512)] = 0.01f + 0.99f * softplus_f(v);
                }
            }
        }
    }
}

// ---------------- z = mu + scale*eps ; emits fp32 z + bf16 zb ----------------
__global__ __launch_bounds__(256) void z2_k(const float* __restrict__ mu,
                                            const float* __restrict__ sc,
                                            float* __restrict__ z,
                                            unsigned short* __restrict__ zb) {
    const uint32_t NH = 2621440u;  // 5242880/2
    uint32_t i = blockIdx.x * 256u + threadIdx.x;
    if (i >= NH) return;
    uint32_t t0 = 2u * i;
    uint32_t o0, o1, p0, p1;
    threefry2x32(0u, 42u, 0u, t0, o0, o1);
    threefry2x32(0u, 42u, 0u, t0 + 1u, p0, p1);
    uint32_t r0 = t0 % 655360u;                  // even; r1 = r0+1 (no wrap)
    float2 mv = *(const float2*)&mu[r0];
    float2 sv = *(const float2*)&sc[r0];
    float z0 = mv.x + sv.x * bits_to_normal(o0 ^ o1);
    float z1 = mv.y + sv.y * bits_to_normal(p0 ^ p1);
    float2 zo; zo.x = z0; zo.y = z1;
    *(float2*)&z[t0] = zo;
    *(uint32_t*)&zb[t0] = cvt2(z0, z1);
}

// ---------------- beta[r] = Wg[r,:] . w2bp + c0 ----------------
__global__ __launch_bounds__(256) void beta2_k(const unsigned short* __restrict__ Wgb,
                                               const float* __restrict__ vec,
                                               const float* __restrict__ c0,
                                               float* __restrict__ beta) {
    int wave = threadIdx.x >> 6, lane = threadIdx.x & 63;
    int r = blockIdx.x * 4 + wave;
    short8 wv = *(const short8*)(Wgb + (size_t)r * 512 + lane * 8);
    float s = 0.f;
#pragma unroll
    for (int e = 0; e < 8; e++) s += vec[lane * 8 + e] * bfu2f((unsigned short)wv[e]);
#pragma unroll
    for (int o = 32; o > 0; o >>= 1) s += __shfl_down(s, o, 64);
    if (lane == 0) beta[r] = s + c0[0];
}

// ---------------- logits v3: one block = 128 q x ALL 160 (s,n) rows ----------
__global__ __launch_bounds__(512) void logits_mfma3_k(const float* __restrict__ Xq,
                                                      const unsigned short* __restrict__ Vb,
                                                      const float* __restrict__ beta,
                                                      float* __restrict__ out) {
    __shared__ unsigned short Vs[160 * 64];  // 20 KB
    __shared__ float bs[160];
    const int u = blockIdx.x + 8 * blockIdx.y;
    const int xcd = u & 7, idx = u >> 3;
    const int b = (idx & 7) * 8 + xcd;
    const int qh = idx >> 3;
    const int tid = threadIdx.x, lane = tid & 63, w = tid >> 6;
    const int wq = w >> 1, wn = w & 1;

    if (tid < 160) {
        int s = tid / 20, n = tid - s * 20;
        bs[tid] = beta[(size_t)(s * 64 + b) * 20 + n];
    }

    const int klane = (lane >> 4) * 8;
    const float* xp[2];
    int qb[2];
#pragma unroll
    for (int qs = 0; qs < 2; qs++) {
        qb[qs] = qh * 128 + wq * 32 + qs * 16;
        int qr = qb[qs] + (lane & 15);
        if (qr > 999) qr = 999;
        xp[qs] = Xq + ((size_t)b * 1000 + qr) * 512 + klane;
    }
    int vrow[5], vswz[5];
#pragma unroll
    for (int nf = 0; nf < 5; nf++) {
        int rr = wn * 80 + nf * 16 + (lane & 15);
        vrow[nf] = rr * 128;
        vswz[nf] = (rr & 7) << 4;
    }

    f32x4 acc[2][5] = {};
    for (int k0 = 0; k0 < 512; k0 += 64) {
        __syncthreads();
        for (int c = tid; c < 640; c += 512) {
            int row = c >> 2, off = (c & 3) * 32;
            int sdiv = row / 20;
            int row_g = row + sdiv * 1260 + b * 20;
            const unsigned short* src = Vb + (size_t)row_g * 512 + k0 + (c & 3) * 16;
            uint4 u0 = *(const uint4*)src;
            uint4 u1 = *(const uint4*)(src + 8);
            int swz = (row & 7) << 4;
            char* base = (char*)Vs + row * 128;
            *(uint4*)(base + (off ^ swz)) = u0;
            *(uint4*)(base + ((off + 16) ^ swz)) = u1;
        }
        __syncthreads();
#pragma unroll
        for (int ks = 0; ks < 2; ks++) {
            int kb = (ks * 32 + klane) * 2;
            short8 bf[5];
#pragma unroll
            for (int nf = 0; nf < 5; nf++)
                bf[nf] = *(const short8*)((const char*)Vs + vrow[nf] + (kb ^ vswz[nf]));
            short8 af[2];
#pragma unroll
            for (int qs = 0; qs < 2; qs++) {
                const float* p = xp[qs] + k0 + ks * 32;
                float4 v0 = *(const float4*)p;
                float4 v1 = *(const float4*)(p + 4);
                uint4 uu;
                uu.x = cvt2(v0.x, v0.y); uu.y = cvt2(v0.z, v0.w);
                uu.z = cvt2(v1.x, v1.y); uu.w = cvt2(v1.z, v1.w);
                __builtin_memcpy(&af[qs], &uu, 16);
            }
#pragma unroll
            for (int qs = 0; qs < 2; qs++)
#pragma unroll
                for (int nf = 0; nf < 5; nf++)
                    acc[qs][nf] = __builtin_amdgcn_mfma_f32_16x16x32_bf16(af[qs], bf[nf], acc[qs][nf], 0, 0, 0);
        }
    }

#pragma unroll
    for (int nf = 0; nf < 5; nf++) {
        int rl = wn * 80 + nf * 16 + (lane & 15);
        int s = rl / 20, n = rl - s * 20;
        float bb = bs[rl];
        size_t ob = (size_t)(s * 64 + b) * 20000;
#pragma unroll
        for (int qs = 0; qs < 2; qs++) {
#pragma unroll
            for (int j = 0; j < 4; j++) {
                int q = qb[qs] + (lane >> 4) * 4 + j;
                if (q < 1000)
                    out[ob + (size_t)q * 20 + n] = acc[qs][nf][j] + bb;
            }
        }
    }
}

extern "C" void kernel_launch(void* const* d_in, const int* in_sizes, int n_in,
                              void* d_out, int out_size, void* d_ws, size_t ws_size,
                              hipStream_t stream) {
    const float* x_context = (const float*)d_in[0];
    const int*   y_context = (const int*)d_in[1];
    const float* x_query   = (const float*)d_in[2];
    const float* Wp  = (const float*)d_in[3];
    const float* bp  = (const float*)d_in[4];
    const float* Wa1 = (const float*)d_in[5];
    const float* ba1 = (const float*)d_in[6];
    const float* Wa2 = (const float*)d_in[7];
    const float* ba2 = (const float*)d_in[8];
    const float* Wd1 = (const float*)d_in[9];
    const float* bd1 = (const float*)d_in[10];
    const float* Wd2 = (const float*)d_in[11];
    const float* bd2 = (const float*)d_in[12];

    float* out    = (float*)d_out;
    float* logits = out;                   // 10,240,000 f
    float* z      = out + 10240000;        // 5,242,880 f
    float* mu     = out + 15482880;        // 655,360 f
    float* sc     = out + 16138240;        // 655,360 f

    // workspace layout
    float* ws   = (float*)d_ws;
    float* cnt  = ws;                       // 1,280 f
    float* beta = cnt + 1280;               // 10,240 f
    float* bv   = beta + 10240;             // 512 f
    float* w2bp = bv + 512;                 // 512 f
    float* c0   = w2bp + 512;               // 1 f (+pad)
    unsigned short* WpTb  = (unsigned short*)(c0 + 63);       // 262,144 sh
    unsigned short* Wa1Tb = WpTb + 262144;                    // 262,144 sh
    unsigned short* Wa2Tb = Wa1Tb + 262144;                   // 524,288 sh
    unsigned short* WdT1b = Wa2Tb + 524288;                   // 262,144 sh
    unsigned short* Wpb   = WdT1b + 262144;                   // 262,144 sh
    unsigned short* Wd2b  = Wpb + 262144;                     // 262,144 sh
    unsigned short* Gtb   = Wd2b + 262144;                    // 262,144 sh
    unsigned short* Abf   = Gtb + 262144;                     // 655,360 sh
    unsigned short* combb = Abf + 655360;                     // 655,360 sh
    unsigned short* hb    = combb + 655360;                   // 655,360 sh
    unsigned short* zb    = hb + 655360;                      // 5,242,880 sh
    unsigned short* Vbf   = zb + 5242880;                     // 5,242,880 sh
    float* big = (float*)(Vbf + 5242880);                     // 5,242,880 f : Apart -> Wgb
    unsigned short* Wgb = (unsigned short*)big;

    // 0) batched prep: transposes, convs, bv/w2bp/c0, class counts
    prep_k<<<dim3(897), 256, 0, stream>>>(Wp, Wa1, Wa2, Wd1, Wd2, bp, bd2, y_context,
                                          WpTb, Wa1Tb, Wa2Tb, WdT1b, Wpb, Wd2b,
                                          bv, w2bp, c0, cnt);
    // 0b) G[d,k] = Wp[d,:]·Wd2[k,:]  (512x512, bf16 out)
    gm2_k<0><<<dim3(4, 8), 256, 0, stream>>>(Wpb, Wd2b, nullptr, nullptr, Gtb, nullptr, nullptr, 512);
    // 1-2) scatter + reduce -> Abf (bf16 1280x512)
    scatter_k<<<dim3(64, 8), 512, 0, stream>>>(x_context, y_context, big /*Apart*/);
    reduce_bf_k<<<dim3(640), 256, 0, stream>>>(big, Abf);
    // 3) comb = relu(A@Wp + cnt*bp)      [MFMA bf16]
    gm2_k<1><<<dim3(4, 20), 256, 0, stream>>>(Abf, WpTb, bp, cnt, combb, nullptr, nullptr, 512);
    // 4) h = gelu(comb@Wa1 + ba1)        [MFMA bf16]
    gm2_k<2><<<dim3(4, 20), 256, 0, stream>>>(combb, Wa1Tb, ba1, nullptr, hb, nullptr, nullptr, 512);
    // 5) stats = h@Wa2 + ba2 -> mu, scale (fp32 outputs)
    gm2_k<3><<<dim3(8, 20), 256, 0, stream>>>(hb, Wa2Tb, ba2, nullptr, nullptr, mu, sc, 1024);
    // 6) z (fp32 out) + zb (bf16)
    z2_k<<<dim3(10240), 256, 0, stream>>>(mu, sc, z, zb);
    // 7) Wg_bf = gelu(z@Wd1 + bd1)
    gm2_k<2><<<dim3(4, 160), 256, 0, stream>>>(zb, WdT1b, bd1, nullptr, Wgb, nullptr, nullptr, 512);
    // 8) V = Wg@G + bv   [folded Wf]
    gm2_k<0><<<dim3(4, 160), 256, 0, stream>>>(Wgb, Gtb, bv, nullptr, Vbf, nullptr, nullptr, 512);
    // 9) beta[r] = Wg[r,:]·w2bp + c0
    beta2_k<<<dim3(2560), 256, 0, stream>>>(Wgb, w2bp, c0, beta);
    // 10) logits
    logits_mfma3_k<<<dim3(8, 64), 512, 0, stream>>>(x_query, Vbf, beta, logits);
}